// Round 4
// baseline (24944.756 us; speedup 1.0000x reference)
//
#include <hip/hip_runtime.h>
#include <math.h>

#define NBS 16
#define NE 3
#define CCH 384
#define HWD 784
#define C4 1536
#define KCL 3
#define NAFF 6
#define PPTS (NE*HWD)      // 2352
#define KM_ITERS 50

// ---------- wave / block reduction helpers ----------
__device__ __forceinline__ float wsum(float v){
  #pragma unroll
  for (int m = 32; m; m >>= 1) v += __shfl_xor(v, m, 64);
  return v;
}
__device__ __forceinline__ float wmin(float v){
  #pragma unroll
  for (int m = 32; m; m >>= 1) v = fminf(v, __shfl_xor(v, m, 64));
  return v;
}
__device__ __forceinline__ float wmax(float v){
  #pragma unroll
  for (int m = 32; m; m >>= 1) v = fmaxf(v, __shfl_xor(v, m, 64));
  return v;
}
__device__ __forceinline__ double shfl_xor_d(double v, int m){
  long long l = __double_as_longlong(v);
  int lo = (int)(l & 0xffffffffLL), hi = (int)(l >> 32);
  lo = __shfl_xor(lo, m, 64); hi = __shfl_xor(hi, m, 64);
  return __longlong_as_double(((long long)hi << 32) | (unsigned long long)(unsigned int)lo);
}
__device__ __forceinline__ double wsumd(double v){
  #pragma unroll
  for (int m = 32; m; m >>= 1) v += shfl_xor_d(v, m);
  return v;
}
__device__ __forceinline__ double wmind(double v){
  #pragma unroll
  for (int m = 32; m; m >>= 1) v = fmin(v, shfl_xor_d(v, m));
  return v;
}
__device__ __forceinline__ double wmaxd(double v){
  #pragma unroll
  for (int m = 32; m; m >>= 1) v = fmax(v, shfl_xor_d(v, m));
  return v;
}
template<int NW>
__device__ float bsum(float v, float* sred, int tid){
  v = wsum(v);
  __syncthreads();
  if ((tid & 63) == 0) sred[tid >> 6] = v;
  __syncthreads();
  if (tid == 0){ float a = 0.f; for (int w = 0; w < NW; w++) a += sred[w]; sred[NW] = a; }
  __syncthreads();
  return sred[NW];
}
template<int NW>
__device__ float bmin(float v, float* sred, int tid){
  v = wmin(v);
  __syncthreads();
  if ((tid & 63) == 0) sred[tid >> 6] = v;
  __syncthreads();
  if (tid == 0){ float a = sred[0]; for (int w = 1; w < NW; w++) a = fminf(a, sred[w]); sred[NW] = a; }
  __syncthreads();
  return sred[NW];
}
template<int NW>
__device__ float bmax(float v, float* sred, int tid){
  v = wmax(v);
  __syncthreads();
  if ((tid & 63) == 0) sred[tid >> 6] = v;
  __syncthreads();
  if (tid == 0){ float a = sred[0]; for (int w = 1; w < NW; w++) a = fmaxf(a, sred[w]); sred[NW] = a; }
  __syncthreads();
  return sred[NW];
}
template<int NW>
__device__ double bsumd(double v, double* sd, int tid){
  v = wsumd(v);
  __syncthreads();
  if ((tid & 63) == 0) sd[tid >> 6] = v;
  __syncthreads();
  if (tid == 0){ double a = 0.0; for (int w = 0; w < NW; w++) a += sd[w]; sd[NW] = a; }
  __syncthreads();
  return sd[NW];
}
template<int NW>
__device__ double bmind(double v, double* sd, int tid){
  v = wmind(v);
  __syncthreads();
  if ((tid & 63) == 0) sd[tid >> 6] = v;
  __syncthreads();
  if (tid == 0){ double a = sd[0]; for (int w = 1; w < NW; w++) a = fmin(a, sd[w]); sd[NW] = a; }
  __syncthreads();
  return sd[NW];
}
template<int NW>
__device__ double bmaxd(double v, double* sd, int tid){
  v = wmaxd(v);
  __syncthreads();
  if ((tid & 63) == 0) sd[tid >> 6] = v;
  __syncthreads();
  if (tid == 0){ double a = sd[0]; for (int w = 1; w < NW; w++) a = fmax(a, sd[w]); sd[NW] = a; }
  __syncthreads();
  return sd[NW];
}

// ---------- Kernel 1: LayerNorm -> fc1 -> GELU -> fc2 (+residual), f64 accumulation ----------
__global__ __launch_bounds__(512) void k_mlp(
    const float* __restrict__ exo, const float* __restrict__ ln_g, const float* __restrict__ ln_b,
    const float* __restrict__ w1, const float* __restrict__ b1,
    const float* __restrict__ w2, const float* __restrict__ b2,
    float* __restrict__ out)
{
  __shared__ __align__(16) float xs[32][CCH];     // xn tile f32 (48KB)
  __shared__ __align__(16) double hs[32][128];    // h chunk f64 (32KB)
  __shared__ __align__(16) float wbuf[32*CCH];    // W staging (48KB)
  int tid = threadIdx.x;
  int t0 = blockIdx.x * 32;

  for (int i = tid; i < 32*CCH; i += 512) ((float*)xs)[i] = exo[(size_t)t0*CCH + i];
  __syncthreads();

  { // LayerNorm in f64 (two-pass, ref formula)
    int wid = tid >> 6, lane = tid & 63;
    for (int tt = 0; tt < 4; tt++) {
      int tok = wid*4 + tt;
      double s = 0.0;
      #pragma unroll
      for (int j = 0; j < 6; j++) s += (double)xs[tok][lane + 64*j];
      s = wsumd(s);
      double mu = s / 384.0;
      double q = 0.0;
      #pragma unroll
      for (int j = 0; j < 6; j++){ double d = (double)xs[tok][lane + 64*j] - mu; q += d*d; }
      q = wsumd(q);
      double sdev = sqrt(q / 384.0 + 1e-5);
      #pragma unroll
      for (int j = 0; j < 6; j++){
        int c = lane + 64*j;
        double v = (double)xs[tok][c];
        xs[tok][c] = (float)((v - mu)/sdev*(double)ln_g[c] + (double)ln_b[c]);
      }
    }
  }
  __syncthreads();

  double acc[24];
  #pragma unroll
  for (int i = 0; i < 24; i++) acc[i] = 0.0;
  int u = tid & 31;
  int tg = tid >> 5;

  for (int jb = 0; jb < 12; jb++) {
    double hacc[8] = {0,0,0,0,0,0,0,0};
    for (int kb = 0; kb < 12; kb++) {
      __syncthreads();
      for (int i = tid; i < 32*128; i += 512) {
        int r = i >> 7, c = i & 127;
        wbuf[r*128 + c] = w1[(size_t)(kb*32 + r)*C4 + jb*128 + c];
      }
      __syncthreads();
      #pragma unroll
      for (int r = 0; r < 32; r++) {
        double xv0 = (double)xs[tg][kb*32 + r];
        double xv1 = (double)xs[tg+16][kb*32 + r];
        float4 wv = *(const float4*)&wbuf[r*128 + u*4];
        double w0 = (double)wv.x, w1d = (double)wv.y, w2d = (double)wv.z, w3 = (double)wv.w;
        hacc[0] += xv0*w0; hacc[1] += xv0*w1d; hacc[2] += xv0*w2d; hacc[3] += xv0*w3;
        hacc[4] += xv1*w0; hacc[5] += xv1*w1d; hacc[6] += xv1*w2d; hacc[7] += xv1*w3;
      }
    }
    #pragma unroll
    for (int jc = 0; jc < 4; jc++) {
      double bb = (double)b1[jb*128 + u*4 + jc];
      double h0 = hacc[jc] + bb;
      double h1 = hacc[4+jc] + bb;
      h0 = 0.5*h0*(1.0 + erf(h0*0.70710678118654752440));
      h1 = 0.5*h1*(1.0 + erf(h1*0.70710678118654752440));
      hs[tg][u*4+jc] = h0;
      hs[tg+16][u*4+jc] = h1;
    }
    for (int kb2 = 0; kb2 < 4; kb2++) {
      __syncthreads();
      for (int i = tid; i < 32*CCH; i += 512) {
        int r = i / CCH, c = i % CCH;
        wbuf[r*CCH + c] = w2[(size_t)(jb*128 + kb2*32 + r)*CCH + c];
      }
      __syncthreads();
      #pragma unroll
      for (int r = 0; r < 32; r++) {
        int jj = kb2*32 + r;
        double h0 = hs[tg][jj];
        double h1 = hs[tg+16][jj];
        const float4* wp = (const float4*)&wbuf[r*CCH + u*12];
        float4 a = wp[0], bq = wp[1], cq = wp[2];
        double wvd[12] = {(double)a.x,(double)a.y,(double)a.z,(double)a.w,
                          (double)bq.x,(double)bq.y,(double)bq.z,(double)bq.w,
                          (double)cq.x,(double)cq.y,(double)cq.z,(double)cq.w};
        #pragma unroll
        for (int z = 0; z < 12; z++) { acc[z] += h0*wvd[z]; acc[12+z] += h1*wvd[z]; }
      }
    }
  }
  #pragma unroll
  for (int half = 0; half < 2; half++) {
    int tok = tg + 16*half;
    int T = t0 + tok;
    int n = T / HWD, p = T % HWD;
    #pragma unroll
    for (int z = 0; z < 12; z++) {
      int c = u*12 + z;
      double y = (double)exo[(size_t)T*CCH + c] + (acc[half*12 + z] + (double)b2[c]);
      out[((size_t)n*CCH + c)*HWD + p] = (float)y;
    }
  }
}

// ---------- Kernel 2: conv3x3 SAME + bias + BN + ReLU, f64 accumulation ----------
__global__ __launch_bounds__(256) void k_conv(
    const float* __restrict__ in, const float* __restrict__ w, const float* __restrict__ bias,
    const float* __restrict__ bng, const float* __restrict__ bnb,
    const float* __restrict__ bnm, const float* __restrict__ bnv,
    float* __restrict__ out)
{
  __shared__ __align__(16) float xt[4][6*28];
  __shared__ __align__(16) float wt[64][4][12];
  int tid = threadIdx.x;
  int blk = blockIdx.x;
  int n = blk / 42; int rem = blk % 42;
  int cob = rem / 7, pxb = rem % 7;
  int co0 = cob*64, r0 = pxb*4;
  int pxg = tid & 15, cog = tid >> 4;
  int rr = pxg >> 2, c0 = (pxg & 3)*7;

  double acc[4][7];
  #pragma unroll
  for (int q = 0; q < 4; q++)
    #pragma unroll
    for (int i = 0; i < 7; i++) acc[q][i] = 0.0;

  for (int cb = 0; cb < 96; cb++) {
    __syncthreads();
    for (int i = tid; i < 4*168; i += 256) {
      int ci = i / 168; int r6 = (i % 168) / 28; int col = i % 28;
      int r = r0 + r6 - 1;
      xt[ci][r6*28 + col] = (r >= 0 && r < 28) ? in[((size_t)n*CCH + cb*4 + ci)*HWD + r*28 + col] : 0.f;
    }
    for (int i = tid; i < 64*4*12; i += 256) {
      int co = i / 48; int ci = (i / 12) & 3; int t12 = i % 12;
      wt[co][ci][t12] = (t12 < 9) ? w[((size_t)(co0 + co)*CCH + cb*4 + ci)*9 + t12] : 0.f;
    }
    __syncthreads();
    #pragma unroll
    for (int ci = 0; ci < 4; ci++) {
      double xrd[3][9];
      #pragma unroll
      for (int dy = 0; dy < 3; dy++)
        #pragma unroll
        for (int dx = 0; dx < 9; dx++) {
          int col = c0 - 1 + dx;
          xrd[dy][dx] = (col >= 0 && col < 28) ? (double)xt[ci][(rr+dy)*28 + col] : 0.0;
        }
      #pragma unroll
      for (int q = 0; q < 4; q++) {
        const float* wp = &wt[cog*4 + q][ci][0];
        double wvd[9];
        #pragma unroll
        for (int t = 0; t < 9; t++) wvd[t] = (double)wp[t];
        #pragma unroll
        for (int i7 = 0; i7 < 7; i7++)
          #pragma unroll
          for (int dy = 0; dy < 3; dy++)
            #pragma unroll
            for (int dx = 0; dx < 3; dx++)
              acc[q][i7] += xrd[dy][i7+dx]*wvd[dy*3+dx];
      }
    }
  }
  #pragma unroll
  for (int q = 0; q < 4; q++) {
    int co = co0 + cog*4 + q;
    double sdev = sqrt((double)bnv[co] + 1e-5);
    double gg = (double)bng[co], bb = (double)bnb[co], mm = (double)bnm[co], bc = (double)bias[co];
    #pragma unroll
    for (int i7 = 0; i7 < 7; i7++) {
      double y = acc[q][i7] + bc;
      y = (y - mm)/sdev*gg + bb;
      y = fmax(y, 0.0);
      out[((size_t)n*CCH + co)*HWD + (r0+rr)*28 + c0 + i7] = (float)y;
    }
  }
}

// ---------- Kernel 3: 1x1 conv head (f64) + logits; writes f64 aff_cam ----------
__global__ __launch_bounds__(256) void k_aff(
    const float* __restrict__ x, const float* __restrict__ fw, const float* __restrict__ fb,
    double* __restrict__ aff_cam, float* __restrict__ logits)
{
  __shared__ float sw[NAFF*CCH];
  __shared__ double sredd[8];
  int tid = threadIdx.x, n = blockIdx.x;
  for (int i = tid; i < NAFF*CCH; i += 256) sw[i] = fw[i];
  __syncthreads();
  double acc[NAFF][4];
  #pragma unroll
  for (int o = 0; o < NAFF; o++)
    #pragma unroll
    for (int j = 0; j < 4; j++) acc[o][j] = 0.0;
  for (int c = 0; c < CCH; c++) {
    double xd[4];
    #pragma unroll
    for (int j = 0; j < 4; j++) {
      int p = tid + j*256;
      xd[j] = (p < HWD) ? (double)x[((size_t)n*CCH + c)*HWD + p] : 0.0;
    }
    #pragma unroll
    for (int o = 0; o < NAFF; o++) {
      double wvd = (double)sw[o*CCH + c];
      #pragma unroll
      for (int j = 0; j < 4; j++) acc[o][j] += wvd*xd[j];
    }
  }
  for (int o = 0; o < NAFF; o++) {
    double s = 0.0;
    double fbd = (double)fb[o];
    #pragma unroll
    for (int j = 0; j < 4; j++) {
      int p = tid + j*256;
      if (p < HWD) {
        double val = acc[o][j] + fbd;
        aff_cam[((size_t)n*NAFF + o)*HWD + p] = val;
        s += val;
      }
    }
    double tot = bsumd<4>(s, sredd, tid);
    if (tid == 0) logits[n*NAFF + o] = (float)(tot / 784.0);
  }
}

// ---------- Kernel 4: ego SAM map (f64 stats) ----------
__global__ __launch_bounds__(256) void k_sam(
    const float* __restrict__ attn, float* __restrict__ sam)
{
  __shared__ double sredd[8];
  int tid = threadIdx.x, b = blockIdx.x;
  const int heads[3] = {0, 1, 3};
  float macc[4] = {0,0,0,0};
  for (int hh = 0; hh < 3; hh++) {
    const float* ap = attn + ((size_t)b*6 + heads[hh])*HWD;
    float av[4]; double s = 0.0;
    #pragma unroll
    for (int j = 0; j < 4; j++){ int p = tid + j*256; av[j] = (p < HWD) ? ap[p] : 0.f; s += (double)av[j]; }
    double tot = bsumd<4>(s, sredd, tid);
    double mean = tot / 784.0;
    #pragma unroll
    for (int j = 0; j < 4; j++){ int p = tid + j*256; if (p < HWD) macc[j] += ((double)av[j] > mean) ? 1.f : 0.f; }
  }
  double mn = 1e300, mx = -1e300;
  double mv[4];
  #pragma unroll
  for (int j = 0; j < 4; j++){
    int p = tid + j*256;
    mv[j] = (double)macc[j] / 3.0;
    if (p < HWD){ mn = fmin(mn, mv[j]); mx = fmax(mx, mv[j]); }
  }
  mn = bmind<4>(mn, sredd, tid);
  mx = bmaxd<4>(mx, sredd, tid);
  #pragma unroll
  for (int j = 0; j < 4; j++){
    int p = tid + j*256;
    if (p < HWD) sam[(size_t)b*HWD + p] = (float)((mv[j]-mn)/(mx-mn+1e-12));
  }
}

// ---------- Kernel 5: per-sample KMeans (f64 decisions) + similarity + IoU ----------
__global__ __launch_bounds__(1024) void k_persample(
    const float* __restrict__ exo, const float* __restrict__ ego,
    const double* __restrict__ aff_cam, const int* __restrict__ labels,
    const float* __restrict__ sam_ws,
    float* __restrict__ out_sim, float* __restrict__ out_exosim,
    float* __restrict__ out_ps, float* __restrict__ out_proto)
{
  __shared__ __align__(16) double s_cent[KCL][CCH];
  __shared__ __align__(16) float  s_centf[KCL][CCH];
  __shared__ float s_wts[PPTS];
  __shared__ float s_wsum[16][KCL][CCH];
  __shared__ float s_wcnt[16][KCL];
  __shared__ double s_csq[KCL];
  __shared__ double s_redd[20];
  __shared__ float s_red[20];
  __shared__ float s_sim[KCL][HWD];
  __shared__ float s_sam[HWD];
  __shared__ int   s_init[KCL];
  __shared__ float s_cnt[KCL];
  __shared__ float s_ps[KCL];
  __shared__ int   s_valid, s_am, s_pflag;

  int tid = threadIdx.x, b = blockIdx.x;
  int wid = tid >> 6, lane = tid & 63;
  int lab = labels[b];

  // P1: cam minmax -> wts, all f64
  for (int e = 0; e < NE; e++) {
    const double* cp = aff_cam + ((size_t)(b*NE + e)*NAFF + lab)*HWD;
    double mn = 1e300, mx = -1e300;
    for (int p = tid; p < HWD; p += 1024){ double v = cp[p]; mn = fmin(mn, v); mx = fmax(mx, v); }
    mn = bmind<16>(mn, s_redd, tid);
    mx = bmaxd<16>(mx, s_redd, tid);
    double den = mx - mn + 1e-10;
    for (int p = tid; p < HWD; p += 1024)
      s_wts[e*HWD + p] = (((cp[p] - mn) / den) > 0.6) ? 1.f : 0.f;
  }
  __syncthreads();
  float nv = 0.f;
  for (int i = tid; i < PPTS; i += 1024) nv += s_wts[i];
  nv = bsum<16>(nv, s_red, tid);
  if (tid == 0) s_valid = (nv >= 3.f) ? 1 : 0;
  __syncthreads();

  // P2: deterministic top-k init
  if (wid == 0) {
    int found = 0; int idx0 = 0, idx1 = 1, idx2 = 2;
    for (int pass = 0; pass < 2 && found < 3; pass++) {
      for (int base = 0; base < PPTS && found < 3; base += 64) {
        int i = base + lane;
        bool hit;
        if (pass == 0) hit = (i < PPTS) && (s_wts[i] > 0.5f);
        else           hit = (i < PPTS) && (s_wts[i] <= 0.5f);
        unsigned long long mask = __ballot(hit);
        while (mask && found < 3) {
          int bit = (int)(__ffsll((unsigned long long)mask)) - 1;
          int id = base + bit;
          if (found == 0) idx0 = id; else if (found == 1) idx1 = id; else idx2 = id;
          found++;
          mask &= mask - 1;
        }
      }
    }
    if (lane == 0){ s_init[0] = idx0; s_init[1] = idx1; s_init[2] = idx2; }
  }
  __syncthreads();
  for (int i = tid; i < KCL*CCH; i += 1024) {
    int k = i / CCH, c = i % CCH;
    int pi = s_init[k];
    s_cent[k][c] = (double)exo[((size_t)(b*NE)*HWD + pi)*CCH + c];
  }
  __syncthreads();

  // P3: KMeans, f64 decisions (p_sq cancels in argmin -> omitted)
  for (int it = 0; it < KM_ITERS; it++) {
    if (wid < KCL) {
      double q = 0.0;
      #pragma unroll
      for (int j = 0; j < 6; j++){ double v = s_cent[wid][lane + 64*j]; q += v*v; }
      q = wsumd(q);
      if (lane == 0) s_csq[wid] = q;
    }
    for (int i = tid; i < 16*KCL*CCH; i += 1024) ((float*)s_wsum)[i] = 0.f;
    if (tid < 16*KCL) ((float*)s_wcnt)[tid] = 0.f;
    __syncthreads();

    float l0[6] = {0,0,0,0,0,0}, l1[6] = {0,0,0,0,0,0}, l2[6] = {0,0,0,0,0,0};
    int c0 = 0, c1 = 0, c2 = 0;
    for (int i = wid; i < PPTS; i += 16) {
      if (s_wts[i] < 0.5f) continue;
      const float* bp = exo + ((size_t)(b*NE)*HWD + i)*CCH;
      float xf[6]; double xd[6];
      #pragma unroll
      for (int j = 0; j < 6; j++){ xf[j] = bp[lane + 64*j]; xd[j] = (double)xf[j]; }
      double dd0 = 0.0, dd1 = 0.0, dd2 = 0.0;
      #pragma unroll
      for (int j = 0; j < 6; j++){
        int c = lane + 64*j;
        dd0 += xd[j]*s_cent[0][c];
        dd1 += xd[j]*s_cent[1][c];
        dd2 += xd[j]*s_cent[2][c];
      }
      dd0 = wsumd(dd0); dd1 = wsumd(dd1); dd2 = wsumd(dd2);
      double e0 = s_csq[0] - 2.0*dd0;
      double e1 = s_csq[1] - 2.0*dd1;
      double e2 = s_csq[2] - 2.0*dd2;
      int a = 0; double best = e0;
      if (e1 < best){ a = 1; best = e1; }
      if (e2 < best){ a = 2; }
      if (a == 0){ for (int j = 0; j < 6; j++) l0[j] += xf[j]; c0++; }
      else if (a == 1){ for (int j = 0; j < 6; j++) l1[j] += xf[j]; c1++; }
      else { for (int j = 0; j < 6; j++) l2[j] += xf[j]; c2++; }
    }
    #pragma unroll
    for (int j = 0; j < 6; j++){
      s_wsum[wid][0][lane + 64*j] = l0[j];
      s_wsum[wid][1][lane + 64*j] = l1[j];
      s_wsum[wid][2][lane + 64*j] = l2[j];
    }
    if (lane == 0){ s_wcnt[wid][0] = (float)c0; s_wcnt[wid][1] = (float)c1; s_wcnt[wid][2] = (float)c2; }
    __syncthreads();
    if (tid < KCL) {
      float cn = 0.f;
      for (int w = 0; w < 16; w++) cn += s_wcnt[w][tid];
      s_cnt[tid] = cn;
    }
    __syncthreads();
    for (int i = tid; i < KCL*CCH; i += 1024) {
      int k = i / CCH, c = i % CCH;
      double s = 0.0;
      for (int w = 0; w < 16; w++) s += (double)s_wsum[w][k][c];
      float cn = s_cnt[k];
      if (cn > 0.f) s_cent[k][c] = s / (double)cn;
    }
    __syncthreads();
  }

  // P4: l2 normalize centroids (f64), then f32 copy
  if (wid < KCL) {
    double q = 0.0;
    #pragma unroll
    for (int j = 0; j < 6; j++){ double v = s_cent[wid][lane + 64*j]; q += v*v; }
    q = wsumd(q);
    double nrm = fmax(sqrt(q), 1e-12);
    #pragma unroll
    for (int j = 0; j < 6; j++) s_cent[wid][lane + 64*j] = s_cent[wid][lane + 64*j] / nrm;
  }
  __syncthreads();
  for (int i = tid; i < KCL*CCH; i += 1024)
    ((float*)s_centf)[i] = (float)((double*)s_cent)[i];
  __syncthreads();
  int valid = s_valid;

  // P5: exo similarity maps
  for (int i = wid; i < PPTS; i += 16) {
    int e = i / HWD, p = i % HWD;
    const float* bp = exo + ((size_t)(b*NE)*HWD + i)*CCH;
    float x[6];
    #pragma unroll
    for (int j = 0; j < 6; j++) x[j] = bp[lane + 64*j];
    float pn = 0.f, d0 = 0.f, d1 = 0.f, d2 = 0.f;
    #pragma unroll
    for (int j = 0; j < 6; j++){
      int c = lane + 64*j; float xv = x[j];
      pn += xv*xv; d0 += xv*s_centf[0][c]; d1 += xv*s_centf[1][c]; d2 += xv*s_centf[2][c];
    }
    pn = wsum(pn); d0 = wsum(d0); d1 = wsum(d1); d2 = wsum(d2);
    float rn = 1.f/fmaxf(sqrtf(pn), 1e-12f);
    if (lane < 3) {
      float dv = (lane == 0) ? d0 : ((lane == 1) ? d1 : d2);
      out_exosim[(((size_t)(b*NE) + e)*KCL + lane)*HWD + p] = valid ? dv*rn : 0.f;
    }
  }

  // P6: ego similarity
  for (int p = wid; p < HWD; p += 16) {
    const float* bp = ego + ((size_t)b*HWD + p)*CCH;
    float x[6];
    #pragma unroll
    for (int j = 0; j < 6; j++) x[j] = bp[lane + 64*j];
    float pn = 0.f, d0 = 0.f, d1 = 0.f, d2 = 0.f;
    #pragma unroll
    for (int j = 0; j < 6; j++){
      int c = lane + 64*j; float xv = x[j];
      pn += xv*xv; d0 += xv*s_centf[0][c]; d1 += xv*s_centf[1][c]; d2 += xv*s_centf[2][c];
    }
    pn = wsum(pn); d0 = wsum(d0); d1 = wsum(d1); d2 = wsum(d2);
    float rn = 1.f/fmaxf(sqrtf(pn), 1e-12f);
    if (lane < 3){
      float dv = (lane == 0) ? d0 : ((lane == 1) ? d1 : d2);
      s_sim[lane][p] = dv*rn;
    }
  }
  for (int p = tid; p < HWD; p += 1024) s_sam[p] = sam_ws[(size_t)b*HWD + p];
  __syncthreads();

  // P7: IoU-style part score
  float ssv = 0.f;
  for (int p = tid; p < HWD; p += 1024) ssv += s_sam[p];
  float sam_mean = bsum<16>(ssv, s_red, tid) * (1.f/784.f);
  float shv = 0.f;
  for (int p = tid; p < HWD; p += 1024) shv += (s_sam[p] > sam_mean) ? 1.f : 0.f;
  float sam_hard_sum = bsum<16>(shv, s_red, tid);

  for (int k = 0; k < KCL; k++) {
    float mn = 1e30f, mx = -1e30f;
    for (int p = tid; p < HWD; p += 1024){ float v = s_sim[k][p]; mn = fminf(mn, v); mx = fmaxf(mx, v); }
    mn = bmin<16>(mn, s_red, tid);
    mx = bmax<16>(mx, s_red, tid);
    float den = mx - mn + 1e-12f;
    float sns = 0.f;
    for (int p = tid; p < HWD; p += 1024) sns += (s_sim[k][p]-mn)/den;
    float mean_n = bsum<16>(sns, s_red, tid) * (1.f/784.f);
    float hsv = 0.f, isv = 0.f;
    for (int p = tid; p < HWD; p += 1024) {
      float sn = (s_sim[k][p]-mn)/den;
      float hd = (sn > mean_n) ? 1.f : 0.f;
      hsv += hd;
      isv += hd*((s_sam[p] > sam_mean) ? 1.f : 0.f);
    }
    float hsum = bsum<16>(hsv, s_red, tid);
    float isum = bsum<16>(isv, s_red, tid);
    float uni = hsum + sam_hard_sum - isum;
    float pk = 0.5f*(isum/(hsum + 1e-12f) + sam_hard_sum/(uni + 1e-12f));
    if (tid == 0) s_ps[k] = valid ? pk : 0.f;
  }
  __syncthreads();

  // P8: outputs
  for (int i = tid; i < KCL*HWD; i += 1024) {
    int k = i / HWD, p = i % HWD;
    out_sim[((size_t)b*KCL + k)*HWD + p] = valid ? s_sim[k][p] : 0.f;
  }
  if (tid < KCL) out_ps[b*KCL + tid] = s_ps[tid];
  if (tid == 0) {
    int am = 0; float pm = s_ps[0];
    if (s_ps[1] > pm){ am = 1; pm = s_ps[1]; }
    if (s_ps[2] > pm){ am = 2; pm = s_ps[2]; }
    s_am = am;
    s_pflag = (valid && pm >= 0.6f) ? 1 : 0;
  }
  __syncthreads();
  for (int c = tid; c < CCH; c += 1024)
    out_proto[(size_t)b*CCH + c] = s_pflag ? s_centf[s_am][c] : 0.f;
}

extern "C" void kernel_launch(void* const* d_in, const int* in_sizes, int n_in,
                              void* d_out, int out_size, void* d_ws, size_t ws_size,
                              hipStream_t stream) {
  const float* ego  = (const float*)d_in[0];
  const float* exo  = (const float*)d_in[1];
  const float* attn = (const float*)d_in[2];
  const int*   lab  = (const int*)d_in[3];
  const float* ln_g = (const float*)d_in[4];
  const float* ln_b = (const float*)d_in[5];
  const float* w1   = (const float*)d_in[6];
  const float* b1   = (const float*)d_in[7];
  const float* w2   = (const float*)d_in[8];
  const float* b2   = (const float*)d_in[9];
  const float* c1w  = (const float*)d_in[10];
  const float* c1b  = (const float*)d_in[11];
  const float* bn1g = (const float*)d_in[12];
  const float* bn1b = (const float*)d_in[13];
  const float* bn1m = (const float*)d_in[14];
  const float* bn1v = (const float*)d_in[15];
  const float* c2w  = (const float*)d_in[16];
  const float* c2b  = (const float*)d_in[17];
  const float* bn2g = (const float*)d_in[18];
  const float* bn2b = (const float*)d_in[19];
  const float* bn2m = (const float*)d_in[20];
  const float* bn2v = (const float*)d_in[21];
  const float* fw   = (const float*)d_in[22];
  const float* fb   = (const float*)d_in[23];

  float* out = (float*)d_out;
  float* o_logits = out;                               // [16,3,6]
  float* o_sim    = out + 288;                         // [16,3,784]
  float* o_exosim = out + 288 + 37632;                 // [16,3,3,784]
  float* o_ps     = out + 288 + 37632 + 112896;        // [16,3]
  float* o_proto  = out + 288 + 37632 + 112896 + 48;   // [16,384]

  float* ws   = (float*)d_ws;
  float* buf0 = ws;                                      // 48*384*784 f32
  float* buf1 = buf0 + (size_t)48*CCH*HWD;               // 48*384*784 f32
  double* affc_d = (double*)(buf1 + (size_t)48*CCH*HWD); // 48*6*784 f64 (8B-aligned offset)
  float* samb = (float*)(affc_d + (size_t)48*NAFF*HWD);  // 16*784 f32

  k_mlp<<<1176, 512, 0, stream>>>(exo, ln_g, ln_b, w1, b1, w2, b2, buf0);
  k_conv<<<2016, 256, 0, stream>>>(buf0, c1w, c1b, bn1g, bn1b, bn1m, bn1v, buf1);
  k_conv<<<2016, 256, 0, stream>>>(buf1, c2w, c2b, bn2g, bn2b, bn2m, bn2v, buf0);
  k_aff<<<48, 256, 0, stream>>>(buf0, fw, fb, affc_d, o_logits);
  k_sam<<<16, 256, 0, stream>>>(attn, samb);
  k_persample<<<16, 1024, 0, stream>>>(exo, ego, affc_d, lab, samb,
                                       o_sim, o_exosim, o_ps, o_proto);
}

// Round 6
// 17634.697 us; speedup vs baseline: 1.4145x; 1.4145x over previous
//
#include <hip/hip_runtime.h>
#include <math.h>

#define NBS 16
#define NE 3
#define CCH 384
#define HWD 784
#define C4 1536
#define KCL 3
#define NAFF 6
#define PPTS (NE*HWD)      // 2352
#define KM_ITERS 50

// ---------- wave / block reduction helpers ----------
__device__ __forceinline__ float wsum(float v){
  #pragma unroll
  for (int m = 32; m; m >>= 1) v += __shfl_xor(v, m, 64);
  return v;
}
__device__ __forceinline__ float wmin(float v){
  #pragma unroll
  for (int m = 32; m; m >>= 1) v = fminf(v, __shfl_xor(v, m, 64));
  return v;
}
__device__ __forceinline__ float wmax(float v){
  #pragma unroll
  for (int m = 32; m; m >>= 1) v = fmaxf(v, __shfl_xor(v, m, 64));
  return v;
}
__device__ __forceinline__ double shfl_xor_d(double v, int m){
  long long l = __double_as_longlong(v);
  int lo = (int)(l & 0xffffffffLL), hi = (int)(l >> 32);
  lo = __shfl_xor(lo, m, 64); hi = __shfl_xor(hi, m, 64);
  return __longlong_as_double(((long long)hi << 32) | (unsigned long long)(unsigned int)lo);
}
__device__ __forceinline__ double wsumd(double v){
  #pragma unroll
  for (int m = 32; m; m >>= 1) v += shfl_xor_d(v, m);
  return v;
}
__device__ __forceinline__ double wmind(double v){
  #pragma unroll
  for (int m = 32; m; m >>= 1) v = fmin(v, shfl_xor_d(v, m));
  return v;
}
__device__ __forceinline__ double wmaxd(double v){
  #pragma unroll
  for (int m = 32; m; m >>= 1) v = fmax(v, shfl_xor_d(v, m));
  return v;
}
template<int NW>
__device__ float bsum(float v, float* sred, int tid){
  v = wsum(v);
  __syncthreads();
  if ((tid & 63) == 0) sred[tid >> 6] = v;
  __syncthreads();
  if (tid == 0){ float a = 0.f; for (int w = 0; w < NW; w++) a += sred[w]; sred[NW] = a; }
  __syncthreads();
  return sred[NW];
}
template<int NW>
__device__ float bmin(float v, float* sred, int tid){
  v = wmin(v);
  __syncthreads();
  if ((tid & 63) == 0) sred[tid >> 6] = v;
  __syncthreads();
  if (tid == 0){ float a = sred[0]; for (int w = 1; w < NW; w++) a = fminf(a, sred[w]); sred[NW] = a; }
  __syncthreads();
  return sred[NW];
}
template<int NW>
__device__ float bmax(float v, float* sred, int tid){
  v = wmax(v);
  __syncthreads();
  if ((tid & 63) == 0) sred[tid >> 6] = v;
  __syncthreads();
  if (tid == 0){ float a = sred[0]; for (int w = 1; w < NW; w++) a = fmaxf(a, sred[w]); sred[NW] = a; }
  __syncthreads();
  return sred[NW];
}
template<int NW>
__device__ double bsumd(double v, double* sd, int tid){
  v = wsumd(v);
  __syncthreads();
  if ((tid & 63) == 0) sd[tid >> 6] = v;
  __syncthreads();
  if (tid == 0){ double a = 0.0; for (int w = 0; w < NW; w++) a += sd[w]; sd[NW] = a; }
  __syncthreads();
  return sd[NW];
}
template<int NW>
__device__ double bmind(double v, double* sd, int tid){
  v = wmind(v);
  __syncthreads();
  if ((tid & 63) == 0) sd[tid >> 6] = v;
  __syncthreads();
  if (tid == 0){ double a = sd[0]; for (int w = 1; w < NW; w++) a = fmin(a, sd[w]); sd[NW] = a; }
  __syncthreads();
  return sd[NW];
}
template<int NW>
__device__ double bmaxd(double v, double* sd, int tid){
  v = wmaxd(v);
  __syncthreads();
  if ((tid & 63) == 0) sd[tid >> 6] = v;
  __syncthreads();
  if (tid == 0){ double a = sd[0]; for (int w = 1; w < NW; w++) a = fmax(a, sd[w]); sd[NW] = a; }
  __syncthreads();
  return sd[NW];
}

// ---------- Kernel 1: LayerNorm -> fc1 -> GELU -> fc2 (+residual), f64 acc, register-blocked ----------
// 16 tokens/block, 256 threads. Weights streamed from global (L2-resident, L1 broadcast);
// LDS only for transposed activations (40KB/block -> 4 blocks/CU).
__global__ __launch_bounds__(256) void k_mlp(
    const float* __restrict__ exo, const float* __restrict__ ln_g, const float* __restrict__ ln_b,
    const float* __restrict__ w1, const float* __restrict__ b1,
    const float* __restrict__ w2, const float* __restrict__ b2,
    float* __restrict__ out)
{
  __shared__ __align__(16) float xs_t[CCH][16];   // [k][token] transposed, 24KB
  __shared__ __align__(16) float hs_t[256][16];   // [k][token] for current jb chunk, 16KB
  int tid = threadIdx.x;
  int t0 = blockIdx.x * 16;
  int wv = tid >> 6, lane = tid & 63;

  // LayerNorm in f64 (two-pass), wave handles 4 tokens; writes transposed f32
  for (int tt = 0; tt < 4; tt++) {
    int tok = wv*4 + tt;
    size_t base = (size_t)(t0 + tok)*CCH;
    float xv[6];
    double s = 0.0;
    #pragma unroll
    for (int j = 0; j < 6; j++){ xv[j] = exo[base + lane + 64*j]; s += (double)xv[j]; }
    s = wsumd(s);
    double mu = s / 384.0;
    double q = 0.0;
    #pragma unroll
    for (int j = 0; j < 6; j++){ double d = (double)xv[j] - mu; q += d*d; }
    q = wsumd(q);
    double sdev = sqrt(q / 384.0 + 1e-5);
    #pragma unroll
    for (int j = 0; j < 6; j++){
      int c = lane + 64*j;
      xs_t[c][tok] = (float)(((double)xv[j] - mu)/sdev*(double)ln_g[c] + (double)ln_b[c]);
    }
  }
  __syncthreads();

  int u = tid & 63;   // GEMM1: cols u*4..u*4+3 of jb chunk; GEMM2: out cols u*6..u*6+5
  int tg = tid >> 6;  // tokens tg*4 .. tg*4+3

  double acc[4][6];
  #pragma unroll
  for (int t = 0; t < 4; t++)
    #pragma unroll
    for (int c = 0; c < 6; c++) acc[t][c] = 0.0;

  for (int jb = 0; jb < 6; jb++) {
    // ---- GEMM1: h[tok][jb*256+u*4+c] = sum_r xn[tok][r]*w1[r][col]
    double hacc[4][4];
    #pragma unroll
    for (int t = 0; t < 4; t++)
      #pragma unroll
      for (int c = 0; c < 4; c++) hacc[t][c] = 0.0;
    const float* w1p = w1 + jb*256 + u*4;
    #pragma unroll 2
    for (int r = 0; r < 384; r++) {
      float4 xq = *(const float4*)&xs_t[r][tg*4];
      float4 wq = *(const float4*)&w1p[(size_t)r*C4];
      double xd[4] = {(double)xq.x,(double)xq.y,(double)xq.z,(double)xq.w};
      double wd[4] = {(double)wq.x,(double)wq.y,(double)wq.z,(double)wq.w};
      #pragma unroll
      for (int t = 0; t < 4; t++)
        #pragma unroll
        for (int c = 0; c < 4; c++) hacc[t][c] += xd[t]*wd[c];
    }
    __syncthreads();   // prior GEMM2 finished reading hs_t
    // bias + exact GELU (f64), store h as f32 (correctly-rounded, matches ref dtype)
    #pragma unroll
    for (int c = 0; c < 4; c++) {
      int col = jb*256 + u*4 + c;
      double bb = (double)b1[col];
      #pragma unroll
      for (int t = 0; t < 4; t++) {
        double h = hacc[t][c] + bb;
        h = 0.5*h*(1.0 + erf(h*0.70710678118654752440));
        hs_t[u*4+c][tg*4+t] = (float)h;
      }
    }
    __syncthreads();
    // ---- GEMM2 partial: acc[tok][outc] += sum_k h[tok][k]*w2[jb*256+k][outc]
    const float* w2p = w2 + (size_t)(jb*256)*CCH + u*6;
    #pragma unroll 2
    for (int k = 0; k < 256; k++) {
      float4 hq = *(const float4*)&hs_t[k][tg*4];
      double hd[4] = {(double)hq.x,(double)hq.y,(double)hq.z,(double)hq.w};
      const float* wr = w2p + (size_t)k*CCH;
      float2 wa = *(const float2*)&wr[0];
      float2 wb = *(const float2*)&wr[2];
      float2 wc = *(const float2*)&wr[4];
      double wd[6] = {(double)wa.x,(double)wa.y,(double)wb.x,(double)wb.y,(double)wc.x,(double)wc.y};
      #pragma unroll
      for (int t = 0; t < 4; t++)
        #pragma unroll
        for (int c = 0; c < 6; c++) acc[t][c] += hd[t]*wd[c];
    }
  }

  // epilogue: residual + b2, write NCHW
  #pragma unroll
  for (int t = 0; t < 4; t++) {
    int T = t0 + tg*4 + t;
    int n = T / HWD, p = T % HWD;
    #pragma unroll
    for (int c6 = 0; c6 < 6; c6++) {
      int c = u*6 + c6;
      double y = (double)exo[(size_t)T*CCH + c] + (acc[t][c6] + (double)b2[c]);
      out[((size_t)n*CCH + c)*HWD + p] = (float)y;
    }
  }
}

// ---------- Kernel 2: conv3x3 SAME + bias + BN + ReLU, f64 acc, halo-padded LDS ----------
__global__ __launch_bounds__(256) void k_conv(
    const float* __restrict__ in, const float* __restrict__ w, const float* __restrict__ bias,
    const float* __restrict__ bng, const float* __restrict__ bnb,
    const float* __restrict__ bnm, const float* __restrict__ bnv,
    float* __restrict__ out)
{
  __shared__ float xt[8*198];        // 8 ci x 6 rows x 33 cols (halo-padded), 6.3KB
  __shared__ float wt[64][8][12];    // 24.6KB
  int tid = threadIdx.x;
  int blk = blockIdx.x;
  int n = blk / 42; int rem = blk % 42;
  int cob = rem / 7, pxb = rem % 7;
  int co0 = cob*64, r0 = pxb*4;
  int pxg = tid & 15, cog = tid >> 4;
  int rr = pxg >> 2, c0 = (pxg & 3)*7;

  double acc[4][7];
  #pragma unroll
  for (int q = 0; q < 4; q++)
    #pragma unroll
    for (int i = 0; i < 7; i++) acc[q][i] = 0.0;

  // 48 slabs x 8 ci = 384 input channels (round-5 bug: was 12 slabs = 96 ch)
  for (int cb = 0; cb < 48; cb++) {
    __syncthreads();
    // stage input tile with zero halo: lds col 0..32 maps W-col -1..31
    for (int i = tid; i < 8*198; i += 256) {
      int ci = i / 198; int r2 = i % 198; int r6 = r2 / 33; int col = r2 % 33;
      int r = r0 + r6 - 1, wc = col - 1;
      xt[i] = (r >= 0 && r < 28 && wc >= 0 && wc < 28)
                ? in[((size_t)n*CCH + cb*8 + ci)*HWD + r*28 + wc] : 0.f;
    }
    for (int i = tid; i < 64*8*12; i += 256) {
      int co = i / 96; int r2 = i % 96; int ci = r2 / 12; int t = r2 % 12;
      wt[co][ci][t] = (t < 9) ? w[((size_t)(co0 + co)*CCH + cb*8 + ci)*9 + t] : 0.f;
    }
    __syncthreads();
    #pragma unroll
    for (int ci = 0; ci < 8; ci++) {
      #pragma unroll
      for (int dy = 0; dy < 3; dy++) {
        const float* xr = &xt[ci*198 + (rr+dy)*33 + c0];
        double xd[9];
        #pragma unroll
        for (int j = 0; j < 9; j++) xd[j] = (double)xr[j];
        #pragma unroll
        for (int q = 0; q < 4; q++) {
          const float* wp = &wt[cog*4 + q][ci][dy*3];
          double w0 = (double)wp[0], w1d = (double)wp[1], w2d = (double)wp[2];
          #pragma unroll
          for (int i7 = 0; i7 < 7; i7++) {
            acc[q][i7] += xd[i7]*w0;
            acc[q][i7] += xd[i7+1]*w1d;
            acc[q][i7] += xd[i7+2]*w2d;
          }
        }
      }
    }
  }
  #pragma unroll
  for (int q = 0; q < 4; q++) {
    int co = co0 + cog*4 + q;
    double sdev = sqrt((double)bnv[co] + 1e-5);
    double gg = (double)bng[co], bb = (double)bnb[co], mm = (double)bnm[co], bc = (double)bias[co];
    #pragma unroll
    for (int i7 = 0; i7 < 7; i7++) {
      double y = acc[q][i7] + bc;
      y = (y - mm)/sdev*gg + bb;
      y = fmax(y, 0.0);
      out[((size_t)n*CCH + co)*HWD + (r0+rr)*28 + c0 + i7] = (float)y;
    }
  }
}

// ---------- Kernel 3: 1x1 conv head (f64) + logits; writes f64 aff_cam ----------
__global__ __launch_bounds__(1024) void k_aff(
    const float* __restrict__ x, const float* __restrict__ fw, const float* __restrict__ fb,
    double* __restrict__ aff_cam, float* __restrict__ logits)
{
  __shared__ double swd[NAFF*CCH];   // 18.4KB, pre-converted weights
  __shared__ double sredd[17];
  int tid = threadIdx.x, n = blockIdx.x;
  for (int i = tid; i < NAFF*CCH; i += 1024) swd[i] = (double)fw[i];
  __syncthreads();
  int px = tid;
  double acc[NAFF] = {0,0,0,0,0,0};
  if (px < HWD) {
    for (int c = 0; c < CCH; c++) {
      double xv = (double)x[((size_t)n*CCH + c)*HWD + px];
      #pragma unroll
      for (int o = 0; o < NAFF; o++) acc[o] += xv * swd[o*CCH + c];
    }
  }
  for (int o = 0; o < NAFF; o++) {
    double val = 0.0;
    if (px < HWD) {
      val = acc[o] + (double)fb[o];
      aff_cam[((size_t)n*NAFF + o)*HWD + px] = val;
    }
    double tot = bsumd<16>(val, sredd, tid);
    if (tid == 0) logits[n*NAFF + o] = (float)(tot / 784.0);
  }
}

// ---------- Kernel 4: ego SAM map (f64 stats) ----------
__global__ __launch_bounds__(256) void k_sam(
    const float* __restrict__ attn, float* __restrict__ sam)
{
  __shared__ double sredd[8];
  int tid = threadIdx.x, b = blockIdx.x;
  const int heads[3] = {0, 1, 3};
  float macc[4] = {0,0,0,0};
  for (int hh = 0; hh < 3; hh++) {
    const float* ap = attn + ((size_t)b*6 + heads[hh])*HWD;
    float av[4]; double s = 0.0;
    #pragma unroll
    for (int j = 0; j < 4; j++){ int p = tid + j*256; av[j] = (p < HWD) ? ap[p] : 0.f; s += (double)av[j]; }
    double tot = bsumd<4>(s, sredd, tid);
    double mean = tot / 784.0;
    #pragma unroll
    for (int j = 0; j < 4; j++){ int p = tid + j*256; if (p < HWD) macc[j] += ((double)av[j] > mean) ? 1.f : 0.f; }
  }
  double mn = 1e300, mx = -1e300;
  double mv[4];
  #pragma unroll
  for (int j = 0; j < 4; j++){
    int p = tid + j*256;
    mv[j] = (double)macc[j] / 3.0;
    if (p < HWD){ mn = fmin(mn, mv[j]); mx = fmax(mx, mv[j]); }
  }
  mn = bmind<4>(mn, sredd, tid);
  mx = bmaxd<4>(mx, sredd, tid);
  #pragma unroll
  for (int j = 0; j < 4; j++){
    int p = tid + j*256;
    if (p < HWD) sam[(size_t)b*HWD + p] = (float)((mv[j]-mn)/(mx-mn+1e-12));
  }
}

// ---------- Kernel 5: per-sample KMeans (f64 decisions) + similarity + IoU ----------
__global__ __launch_bounds__(1024) void k_persample(
    const float* __restrict__ exo, const float* __restrict__ ego,
    const double* __restrict__ aff_cam, const int* __restrict__ labels,
    const float* __restrict__ sam_ws,
    float* __restrict__ out_sim, float* __restrict__ out_exosim,
    float* __restrict__ out_ps, float* __restrict__ out_proto)
{
  __shared__ __align__(16) double s_cent[KCL][CCH];
  __shared__ __align__(16) float  s_centf[KCL][CCH];
  __shared__ float s_wts[PPTS];
  __shared__ float s_wsum[16][KCL][CCH];
  __shared__ float s_wcnt[16][KCL];
  __shared__ double s_csq[KCL];
  __shared__ double s_redd[20];
  __shared__ float s_red[20];
  __shared__ float s_sim[KCL][HWD];
  __shared__ float s_sam[HWD];
  __shared__ int   s_init[KCL];
  __shared__ float s_cnt[KCL];
  __shared__ float s_ps[KCL];
  __shared__ int   s_valid, s_am, s_pflag;

  int tid = threadIdx.x, b = blockIdx.x;
  int wid = tid >> 6, lane = tid & 63;
  int lab = labels[b];

  // P1: cam minmax -> wts, all f64
  for (int e = 0; e < NE; e++) {
    const double* cp = aff_cam + ((size_t)(b*NE + e)*NAFF + lab)*HWD;
    double mn = 1e300, mx = -1e300;
    for (int p = tid; p < HWD; p += 1024){ double v = cp[p]; mn = fmin(mn, v); mx = fmax(mx, v); }
    mn = bmind<16>(mn, s_redd, tid);
    mx = bmaxd<16>(mx, s_redd, tid);
    double den = mx - mn + 1e-10;
    for (int p = tid; p < HWD; p += 1024)
      s_wts[e*HWD + p] = (((cp[p] - mn) / den) > 0.6) ? 1.f : 0.f;
  }
  __syncthreads();
  float nv = 0.f;
  for (int i = tid; i < PPTS; i += 1024) nv += s_wts[i];
  nv = bsum<16>(nv, s_red, tid);
  if (tid == 0) s_valid = (nv >= 3.f) ? 1 : 0;
  __syncthreads();

  // P2: deterministic top-k init
  if (wid == 0) {
    int found = 0; int idx0 = 0, idx1 = 1, idx2 = 2;
    for (int pass = 0; pass < 2 && found < 3; pass++) {
      for (int base = 0; base < PPTS && found < 3; base += 64) {
        int i = base + lane;
        bool hit;
        if (pass == 0) hit = (i < PPTS) && (s_wts[i] > 0.5f);
        else           hit = (i < PPTS) && (s_wts[i] <= 0.5f);
        unsigned long long mask = __ballot(hit);
        while (mask && found < 3) {
          int bit = (int)(__ffsll((unsigned long long)mask)) - 1;
          int id = base + bit;
          if (found == 0) idx0 = id; else if (found == 1) idx1 = id; else idx2 = id;
          found++;
          mask &= mask - 1;
        }
      }
    }
    if (lane == 0){ s_init[0] = idx0; s_init[1] = idx1; s_init[2] = idx2; }
  }
  __syncthreads();
  for (int i = tid; i < KCL*CCH; i += 1024) {
    int k = i / CCH, c = i % CCH;
    int pi = s_init[k];
    s_cent[k][c] = (double)exo[((size_t)(b*NE)*HWD + pi)*CCH + c];
  }
  __syncthreads();

  // P3: KMeans, f64 decisions (p_sq cancels in argmin -> omitted)
  for (int it = 0; it < KM_ITERS; it++) {
    if (wid < KCL) {
      double q = 0.0;
      #pragma unroll
      for (int j = 0; j < 6; j++){ double v = s_cent[wid][lane + 64*j]; q += v*v; }
      q = wsumd(q);
      if (lane == 0) s_csq[wid] = q;
    }
    for (int i = tid; i < 16*KCL*CCH; i += 1024) ((float*)s_wsum)[i] = 0.f;
    if (tid < 16*KCL) ((float*)s_wcnt)[tid] = 0.f;
    __syncthreads();

    float l0[6] = {0,0,0,0,0,0}, l1[6] = {0,0,0,0,0,0}, l2[6] = {0,0,0,0,0,0};
    int c0 = 0, c1 = 0, c2 = 0;
    for (int i = wid; i < PPTS; i += 16) {
      if (s_wts[i] < 0.5f) continue;
      const float* bp = exo + ((size_t)(b*NE)*HWD + i)*CCH;
      float xf[6]; double xd[6];
      #pragma unroll
      for (int j = 0; j < 6; j++){ xf[j] = bp[lane + 64*j]; xd[j] = (double)xf[j]; }
      double dd0 = 0.0, dd1 = 0.0, dd2 = 0.0;
      #pragma unroll
      for (int j = 0; j < 6; j++){
        int c = lane + 64*j;
        dd0 += xd[j]*s_cent[0][c];
        dd1 += xd[j]*s_cent[1][c];
        dd2 += xd[j]*s_cent[2][c];
      }
      dd0 = wsumd(dd0); dd1 = wsumd(dd1); dd2 = wsumd(dd2);
      double e0 = s_csq[0] - 2.0*dd0;
      double e1 = s_csq[1] - 2.0*dd1;
      double e2 = s_csq[2] - 2.0*dd2;
      int a = 0; double best = e0;
      if (e1 < best){ a = 1; best = e1; }
      if (e2 < best){ a = 2; }
      if (a == 0){ for (int j = 0; j < 6; j++) l0[j] += xf[j]; c0++; }
      else if (a == 1){ for (int j = 0; j < 6; j++) l1[j] += xf[j]; c1++; }
      else { for (int j = 0; j < 6; j++) l2[j] += xf[j]; c2++; }
    }
    #pragma unroll
    for (int j = 0; j < 6; j++){
      s_wsum[wid][0][lane + 64*j] = l0[j];
      s_wsum[wid][1][lane + 64*j] = l1[j];
      s_wsum[wid][2][lane + 64*j] = l2[j];
    }
    if (lane == 0){ s_wcnt[wid][0] = (float)c0; s_wcnt[wid][1] = (float)c1; s_wcnt[wid][2] = (float)c2; }
    __syncthreads();
    if (tid < KCL) {
      float cn = 0.f;
      for (int w = 0; w < 16; w++) cn += s_wcnt[w][tid];
      s_cnt[tid] = cn;
    }
    __syncthreads();
    for (int i = tid; i < KCL*CCH; i += 1024) {
      int k = i / CCH, c = i % CCH;
      double s = 0.0;
      for (int w = 0; w < 16; w++) s += (double)s_wsum[w][k][c];
      float cn = s_cnt[k];
      if (cn > 0.f) s_cent[k][c] = s / (double)cn;
    }
    __syncthreads();
  }

  // P4: l2 normalize centroids (f64), then f32 copy
  if (wid < KCL) {
    double q = 0.0;
    #pragma unroll
    for (int j = 0; j < 6; j++){ double v = s_cent[wid][lane + 64*j]; q += v*v; }
    q = wsumd(q);
    double nrm = fmax(sqrt(q), 1e-12);
    #pragma unroll
    for (int j = 0; j < 6; j++) s_cent[wid][lane + 64*j] = s_cent[wid][lane + 64*j] / nrm;
  }
  __syncthreads();
  for (int i = tid; i < KCL*CCH; i += 1024)
    ((float*)s_centf)[i] = (float)((double*)s_cent)[i];
  __syncthreads();
  int valid = s_valid;

  // P5: exo similarity maps
  for (int i = wid; i < PPTS; i += 16) {
    int e = i / HWD, p = i % HWD;
    const float* bp = exo + ((size_t)(b*NE)*HWD + i)*CCH;
    float x[6];
    #pragma unroll
    for (int j = 0; j < 6; j++) x[j] = bp[lane + 64*j];
    float pn = 0.f, d0 = 0.f, d1 = 0.f, d2 = 0.f;
    #pragma unroll
    for (int j = 0; j < 6; j++){
      int c = lane + 64*j; float xv = x[j];
      pn += xv*xv; d0 += xv*s_centf[0][c]; d1 += xv*s_centf[1][c]; d2 += xv*s_centf[2][c];
    }
    pn = wsum(pn); d0 = wsum(d0); d1 = wsum(d1); d2 = wsum(d2);
    float rn = 1.f/fmaxf(sqrtf(pn), 1e-12f);
    if (lane < 3) {
      float dv = (lane == 0) ? d0 : ((lane == 1) ? d1 : d2);
      out_exosim[(((size_t)(b*NE) + e)*KCL + lane)*HWD + p] = valid ? dv*rn : 0.f;
    }
  }

  // P6: ego similarity
  for (int p = wid; p < HWD; p += 16) {
    const float* bp = ego + ((size_t)b*HWD + p)*CCH;
    float x[6];
    #pragma unroll
    for (int j = 0; j < 6; j++) x[j] = bp[lane + 64*j];
    float pn = 0.f, d0 = 0.f, d1 = 0.f, d2 = 0.f;
    #pragma unroll
    for (int j = 0; j < 6; j++){
      int c = lane + 64*j; float xv = x[j];
      pn += xv*xv; d0 += xv*s_centf[0][c]; d1 += xv*s_centf[1][c]; d2 += xv*s_centf[2][c];
    }
    pn = wsum(pn); d0 = wsum(d0); d1 = wsum(d1); d2 = wsum(d2);
    float rn = 1.f/fmaxf(sqrtf(pn), 1e-12f);
    if (lane < 3){
      float dv = (lane == 0) ? d0 : ((lane == 1) ? d1 : d2);
      s_sim[lane][p] = dv*rn;
    }
  }
  for (int p = tid; p < HWD; p += 1024) s_sam[p] = sam_ws[(size_t)b*HWD + p];
  __syncthreads();

  // P7: IoU-style part score
  float ssv = 0.f;
  for (int p = tid; p < HWD; p += 1024) ssv += s_sam[p];
  float sam_mean = bsum<16>(ssv, s_red, tid) * (1.f/784.f);
  float shv = 0.f;
  for (int p = tid; p < HWD; p += 1024) shv += (s_sam[p] > sam_mean) ? 1.f : 0.f;
  float sam_hard_sum = bsum<16>(shv, s_red, tid);

  for (int k = 0; k < KCL; k++) {
    float mn = 1e30f, mx = -1e30f;
    for (int p = tid; p < HWD; p += 1024){ float v = s_sim[k][p]; mn = fminf(mn, v); mx = fmaxf(mx, v); }
    mn = bmin<16>(mn, s_red, tid);
    mx = bmax<16>(mx, s_red, tid);
    float den = mx - mn + 1e-12f;
    float sns = 0.f;
    for (int p = tid; p < HWD; p += 1024) sns += (s_sim[k][p]-mn)/den;
    float mean_n = bsum<16>(sns, s_red, tid) * (1.f/784.f);
    float hsv = 0.f, isv = 0.f;
    for (int p = tid; p < HWD; p += 1024) {
      float sn = (s_sim[k][p]-mn)/den;
      float hd = (sn > mean_n) ? 1.f : 0.f;
      hsv += hd;
      isv += hd*((s_sam[p] > sam_mean) ? 1.f : 0.f);
    }
    float hsum = bsum<16>(hsv, s_red, tid);
    float isum = bsum<16>(isv, s_red, tid);
    float uni = hsum + sam_hard_sum - isum;
    float pk = 0.5f*(isum/(hsum + 1e-12f) + sam_hard_sum/(uni + 1e-12f));
    if (tid == 0) s_ps[k] = valid ? pk : 0.f;
  }
  __syncthreads();

  // P8: outputs
  for (int i = tid; i < KCL*HWD; i += 1024) {
    int k = i / HWD, p = i % HWD;
    out_sim[((size_t)b*KCL + k)*HWD + p] = valid ? s_sim[k][p] : 0.f;
  }
  if (tid < KCL) out_ps[b*KCL + tid] = s_ps[tid];
  if (tid == 0) {
    int am = 0; float pm = s_ps[0];
    if (s_ps[1] > pm){ am = 1; pm = s_ps[1]; }
    if (s_ps[2] > pm){ am = 2; pm = s_ps[2]; }
    s_am = am;
    s_pflag = (valid && pm >= 0.6f) ? 1 : 0;
  }
  __syncthreads();
  for (int c = tid; c < CCH; c += 1024)
    out_proto[(size_t)b*CCH + c] = s_pflag ? s_centf[s_am][c] : 0.f;
}

extern "C" void kernel_launch(void* const* d_in, const int* in_sizes, int n_in,
                              void* d_out, int out_size, void* d_ws, size_t ws_size,
                              hipStream_t stream) {
  const float* ego  = (const float*)d_in[0];
  const float* exo  = (const float*)d_in[1];
  const float* attn = (const float*)d_in[2];
  const int*   lab  = (const int*)d_in[3];
  const float* ln_g = (const float*)d_in[4];
  const float* ln_b = (const float*)d_in[5];
  const float* w1   = (const float*)d_in[6];
  const float* b1   = (const float*)d_in[7];
  const float* w2   = (const float*)d_in[8];
  const float* b2   = (const float*)d_in[9];
  const float* c1w  = (const float*)d_in[10];
  const float* c1b  = (const float*)d_in[11];
  const float* bn1g = (const float*)d_in[12];
  const float* bn1b = (const float*)d_in[13];
  const float* bn1m = (const float*)d_in[14];
  const float* bn1v = (const float*)d_in[15];
  const float* c2w  = (const float*)d_in[16];
  const float* c2b  = (const float*)d_in[17];
  const float* bn2g = (const float*)d_in[18];
  const float* bn2b = (const float*)d_in[19];
  const float* bn2m = (const float*)d_in[20];
  const float* bn2v = (const float*)d_in[21];
  const float* fw   = (const float*)d_in[22];
  const float* fb   = (const float*)d_in[23];

  float* out = (float*)d_out;
  float* o_logits = out;                               // [16,3,6]
  float* o_sim    = out + 288;                         // [16,3,784]
  float* o_exosim = out + 288 + 37632;                 // [16,3,3,784]
  float* o_ps     = out + 288 + 37632 + 112896;        // [16,3]
  float* o_proto  = out + 288 + 37632 + 112896 + 48;   // [16,384]

  float* ws   = (float*)d_ws;
  float* buf0 = ws;                                      // 48*384*784 f32
  float* buf1 = buf0 + (size_t)48*CCH*HWD;               // 48*384*784 f32
  double* affc_d = (double*)(buf1 + (size_t)48*CCH*HWD); // 48*6*784 f64 (8B-aligned offset)
  float* samb = (float*)(affc_d + (size_t)48*NAFF*HWD);  // 16*784 f32

  k_mlp<<<2352, 256, 0, stream>>>(exo, ln_g, ln_b, w1, b1, w2, b2, buf0);
  k_conv<<<2016, 256, 0, stream>>>(buf0, c1w, c1b, bn1g, bn1b, bn1m, bn1v, buf1);
  k_conv<<<2016, 256, 0, stream>>>(buf1, c2w, c2b, bn2g, bn2b, bn2m, bn2v, buf0);
  k_aff<<<48, 1024, 0, stream>>>(buf0, fw, fb, affc_d, o_logits);
  k_sam<<<16, 256, 0, stream>>>(attn, samb);
  k_persample<<<16, 1024, 0, stream>>>(exo, ego, affc_d, lab, samb,
                                       o_sim, o_exosim, o_ps, o_proto);
}

// Round 7
// 14006.049 us; speedup vs baseline: 1.7810x; 1.2591x over previous
//
#include <hip/hip_runtime.h>
#include <math.h>

#define NBS 16
#define NE 3
#define CCH 384
#define HWD 784
#define C4 1536
#define KCL 3
#define NAFF 6
#define PPTS (NE*HWD)      // 2352
#define KM_ITERS 50

// ---------- wave / block reduction helpers ----------
__device__ __forceinline__ float wsum(float v){
  #pragma unroll
  for (int m = 32; m; m >>= 1) v += __shfl_xor(v, m, 64);
  return v;
}
__device__ __forceinline__ float wmin(float v){
  #pragma unroll
  for (int m = 32; m; m >>= 1) v = fminf(v, __shfl_xor(v, m, 64));
  return v;
}
__device__ __forceinline__ float wmax(float v){
  #pragma unroll
  for (int m = 32; m; m >>= 1) v = fmaxf(v, __shfl_xor(v, m, 64));
  return v;
}
__device__ __forceinline__ double shfl_xor_d(double v, int m){
  long long l = __double_as_longlong(v);
  int lo = (int)(l & 0xffffffffLL), hi = (int)(l >> 32);
  lo = __shfl_xor(lo, m, 64); hi = __shfl_xor(hi, m, 64);
  return __longlong_as_double(((long long)hi << 32) | (unsigned long long)(unsigned int)lo);
}
__device__ __forceinline__ double wsumd(double v){
  #pragma unroll
  for (int m = 32; m; m >>= 1) v += shfl_xor_d(v, m);
  return v;
}
__device__ __forceinline__ double wmind(double v){
  #pragma unroll
  for (int m = 32; m; m >>= 1) v = fmin(v, shfl_xor_d(v, m));
  return v;
}
__device__ __forceinline__ double wmaxd(double v){
  #pragma unroll
  for (int m = 32; m; m >>= 1) v = fmax(v, shfl_xor_d(v, m));
  return v;
}
template<int NW>
__device__ float bsum(float v, float* sred, int tid){
  v = wsum(v);
  __syncthreads();
  if ((tid & 63) == 0) sred[tid >> 6] = v;
  __syncthreads();
  if (tid == 0){ float a = 0.f; for (int w = 0; w < NW; w++) a += sred[w]; sred[NW] = a; }
  __syncthreads();
  return sred[NW];
}
template<int NW>
__device__ float bmin(float v, float* sred, int tid){
  v = wmin(v);
  __syncthreads();
  if ((tid & 63) == 0) sred[tid >> 6] = v;
  __syncthreads();
  if (tid == 0){ float a = sred[0]; for (int w = 1; w < NW; w++) a = fminf(a, sred[w]); sred[NW] = a; }
  __syncthreads();
  return sred[NW];
}
template<int NW>
__device__ float bmax(float v, float* sred, int tid){
  v = wmax(v);
  __syncthreads();
  if ((tid & 63) == 0) sred[tid >> 6] = v;
  __syncthreads();
  if (tid == 0){ float a = sred[0]; for (int w = 1; w < NW; w++) a = fmaxf(a, sred[w]); sred[NW] = a; }
  __syncthreads();
  return sred[NW];
}
template<int NW>
__device__ double bsumd(double v, double* sd, int tid){
  v = wsumd(v);
  __syncthreads();
  if ((tid & 63) == 0) sd[tid >> 6] = v;
  __syncthreads();
  if (tid == 0){ double a = 0.0; for (int w = 0; w < NW; w++) a += sd[w]; sd[NW] = a; }
  __syncthreads();
  return sd[NW];
}
template<int NW>
__device__ double bmind(double v, double* sd, int tid){
  v = wmind(v);
  __syncthreads();
  if ((tid & 63) == 0) sd[tid >> 6] = v;
  __syncthreads();
  if (tid == 0){ double a = sd[0]; for (int w = 1; w < NW; w++) a = fmin(a, sd[w]); sd[NW] = a; }
  __syncthreads();
  return sd[NW];
}
template<int NW>
__device__ double bmaxd(double v, double* sd, int tid){
  v = wmaxd(v);
  __syncthreads();
  if ((tid & 63) == 0) sd[tid >> 6] = v;
  __syncthreads();
  if (tid == 0){ double a = sd[0]; for (int w = 1; w < NW; w++) a = fmax(a, sd[w]); sd[NW] = a; }
  __syncthreads();
  return sd[NW];
}

// ---------- Kernel 1: LayerNorm -> fc1 -> GELU -> fc2 (+residual), f64 acc, register-blocked ----------
__global__ __launch_bounds__(256) void k_mlp(
    const float* __restrict__ exo, const float* __restrict__ ln_g, const float* __restrict__ ln_b,
    const float* __restrict__ w1, const float* __restrict__ b1,
    const float* __restrict__ w2, const float* __restrict__ b2,
    float* __restrict__ out)
{
  __shared__ __align__(16) float xs_t[CCH][16];   // [k][token] transposed, 24KB
  __shared__ __align__(16) float hs_t[256][16];   // [k][token] for current jb chunk, 16KB
  int tid = threadIdx.x;
  int t0 = blockIdx.x * 16;
  int wv = tid >> 6, lane = tid & 63;

  // LayerNorm in f64 (two-pass), wave handles 4 tokens; writes transposed f32
  for (int tt = 0; tt < 4; tt++) {
    int tok = wv*4 + tt;
    size_t base = (size_t)(t0 + tok)*CCH;
    float xv[6];
    double s = 0.0;
    #pragma unroll
    for (int j = 0; j < 6; j++){ xv[j] = exo[base + lane + 64*j]; s += (double)xv[j]; }
    s = wsumd(s);
    double mu = s / 384.0;
    double q = 0.0;
    #pragma unroll
    for (int j = 0; j < 6; j++){ double d = (double)xv[j] - mu; q += d*d; }
    q = wsumd(q);
    double sdev = sqrt(q / 384.0 + 1e-5);
    #pragma unroll
    for (int j = 0; j < 6; j++){
      int c = lane + 64*j;
      xs_t[c][tok] = (float)(((double)xv[j] - mu)/sdev*(double)ln_g[c] + (double)ln_b[c]);
    }
  }
  __syncthreads();

  int u = tid & 63;   // GEMM1: cols u*4..u*4+3 of jb chunk; GEMM2: out cols u*6..u*6+5
  int tg = tid >> 6;  // tokens tg*4 .. tg*4+3

  double acc[4][6];
  #pragma unroll
  for (int t = 0; t < 4; t++)
    #pragma unroll
    for (int c = 0; c < 6; c++) acc[t][c] = 0.0;

  for (int jb = 0; jb < 6; jb++) {
    // ---- GEMM1: h[tok][jb*256+u*4+c] = sum_r xn[tok][r]*w1[r][col]
    double hacc[4][4];
    #pragma unroll
    for (int t = 0; t < 4; t++)
      #pragma unroll
      for (int c = 0; c < 4; c++) hacc[t][c] = 0.0;
    const float* w1p = w1 + jb*256 + u*4;
    #pragma unroll 2
    for (int r = 0; r < 384; r++) {
      float4 xq = *(const float4*)&xs_t[r][tg*4];
      float4 wq = *(const float4*)&w1p[(size_t)r*C4];
      double xd[4] = {(double)xq.x,(double)xq.y,(double)xq.z,(double)xq.w};
      double wd[4] = {(double)wq.x,(double)wq.y,(double)wq.z,(double)wq.w};
      #pragma unroll
      for (int t = 0; t < 4; t++)
        #pragma unroll
        for (int c = 0; c < 4; c++) hacc[t][c] += xd[t]*wd[c];
    }
    __syncthreads();   // prior GEMM2 finished reading hs_t
    // bias + exact GELU (f64), store h as f32 (correctly-rounded, matches ref dtype)
    #pragma unroll
    for (int c = 0; c < 4; c++) {
      int col = jb*256 + u*4 + c;
      double bb = (double)b1[col];
      #pragma unroll
      for (int t = 0; t < 4; t++) {
        double h = hacc[t][c] + bb;
        h = 0.5*h*(1.0 + erf(h*0.70710678118654752440));
        hs_t[u*4+c][tg*4+t] = (float)h;
      }
    }
    __syncthreads();
    // ---- GEMM2 partial: acc[tok][outc] += sum_k h[tok][k]*w2[jb*256+k][outc]
    const float* w2p = w2 + (size_t)(jb*256)*CCH + u*6;
    #pragma unroll 2
    for (int k = 0; k < 256; k++) {
      float4 hq = *(const float4*)&hs_t[k][tg*4];
      double hd[4] = {(double)hq.x,(double)hq.y,(double)hq.z,(double)hq.w};
      const float* wr = w2p + (size_t)k*CCH;
      float2 wa = *(const float2*)&wr[0];
      float2 wb = *(const float2*)&wr[2];
      float2 wc = *(const float2*)&wr[4];
      double wd[6] = {(double)wa.x,(double)wa.y,(double)wb.x,(double)wb.y,(double)wc.x,(double)wc.y};
      #pragma unroll
      for (int t = 0; t < 4; t++)
        #pragma unroll
        for (int c = 0; c < 6; c++) acc[t][c] += hd[t]*wd[c];
    }
  }

  // epilogue: residual + b2, write NCHW
  #pragma unroll
  for (int t = 0; t < 4; t++) {
    int T = t0 + tg*4 + t;
    int n = T / HWD, p = T % HWD;
    #pragma unroll
    for (int c6 = 0; c6 < 6; c6++) {
      int c = u*6 + c6;
      double y = (double)exo[(size_t)T*CCH + c] + (acc[t][c6] + (double)b2[c]);
      out[((size_t)n*CCH + c)*HWD + p] = (float)y;
    }
  }
}

// ---------- Kernel 2: conv3x3 SAME + bias + BN + ReLU, f64 acc, halo-padded LDS ----------
__global__ __launch_bounds__(256) void k_conv(
    const float* __restrict__ in, const float* __restrict__ w, const float* __restrict__ bias,
    const float* __restrict__ bng, const float* __restrict__ bnb,
    const float* __restrict__ bnm, const float* __restrict__ bnv,
    float* __restrict__ out)
{
  __shared__ float xt[8*198];        // 8 ci x 6 rows x 33 cols (halo-padded), 6.3KB
  __shared__ float wt[64][8][12];    // 24.6KB
  int tid = threadIdx.x;
  int blk = blockIdx.x;
  int n = blk / 42; int rem = blk % 42;
  int cob = rem / 7, pxb = rem % 7;
  int co0 = cob*64, r0 = pxb*4;
  int pxg = tid & 15, cog = tid >> 4;
  int rr = pxg >> 2, c0 = (pxg & 3)*7;

  double acc[4][7];
  #pragma unroll
  for (int q = 0; q < 4; q++)
    #pragma unroll
    for (int i = 0; i < 7; i++) acc[q][i] = 0.0;

  for (int cb = 0; cb < 48; cb++) {
    __syncthreads();
    for (int i = tid; i < 8*198; i += 256) {
      int ci = i / 198; int r2 = i % 198; int r6 = r2 / 33; int col = r2 % 33;
      int r = r0 + r6 - 1, wc = col - 1;
      xt[i] = (r >= 0 && r < 28 && wc >= 0 && wc < 28)
                ? in[((size_t)n*CCH + cb*8 + ci)*HWD + r*28 + wc] : 0.f;
    }
    for (int i = tid; i < 64*8*12; i += 256) {
      int co = i / 96; int r2 = i % 96; int ci = r2 / 12; int t = r2 % 12;
      wt[co][ci][t] = (t < 9) ? w[((size_t)(co0 + co)*CCH + cb*8 + ci)*9 + t] : 0.f;
    }
    __syncthreads();
    #pragma unroll
    for (int ci = 0; ci < 8; ci++) {
      #pragma unroll
      for (int dy = 0; dy < 3; dy++) {
        const float* xr = &xt[ci*198 + (rr+dy)*33 + c0];
        double xd[9];
        #pragma unroll
        for (int j = 0; j < 9; j++) xd[j] = (double)xr[j];
        #pragma unroll
        for (int q = 0; q < 4; q++) {
          const float* wp = &wt[cog*4 + q][ci][dy*3];
          double w0 = (double)wp[0], w1d = (double)wp[1], w2d = (double)wp[2];
          #pragma unroll
          for (int i7 = 0; i7 < 7; i7++) {
            acc[q][i7] += xd[i7]*w0;
            acc[q][i7] += xd[i7+1]*w1d;
            acc[q][i7] += xd[i7+2]*w2d;
          }
        }
      }
    }
  }
  #pragma unroll
  for (int q = 0; q < 4; q++) {
    int co = co0 + cog*4 + q;
    double sdev = sqrt((double)bnv[co] + 1e-5);
    double gg = (double)bng[co], bb = (double)bnb[co], mm = (double)bnm[co], bc = (double)bias[co];
    #pragma unroll
    for (int i7 = 0; i7 < 7; i7++) {
      double y = acc[q][i7] + bc;
      y = (y - mm)/sdev*gg + bb;
      y = fmax(y, 0.0);
      out[((size_t)n*CCH + co)*HWD + (r0+rr)*28 + c0 + i7] = (float)y;
    }
  }
}

// ---------- Kernel 3: 1x1 conv head (f64) + logits; writes f64 aff_cam ----------
__global__ __launch_bounds__(1024) void k_aff(
    const float* __restrict__ x, const float* __restrict__ fw, const float* __restrict__ fb,
    double* __restrict__ aff_cam, float* __restrict__ logits)
{
  __shared__ double swd[NAFF*CCH];   // 18.4KB, pre-converted weights
  __shared__ double sredd[17];
  int tid = threadIdx.x, n = blockIdx.x;
  for (int i = tid; i < NAFF*CCH; i += 1024) swd[i] = (double)fw[i];
  __syncthreads();
  int px = tid;
  double acc[NAFF] = {0,0,0,0,0,0};
  if (px < HWD) {
    for (int c = 0; c < CCH; c++) {
      double xv = (double)x[((size_t)n*CCH + c)*HWD + px];
      #pragma unroll
      for (int o = 0; o < NAFF; o++) acc[o] += xv * swd[o*CCH + c];
    }
  }
  for (int o = 0; o < NAFF; o++) {
    double val = 0.0;
    if (px < HWD) {
      val = acc[o] + (double)fb[o];
      aff_cam[((size_t)n*NAFF + o)*HWD + px] = val;
    }
    double tot = bsumd<16>(val, sredd, tid);
    if (tid == 0) logits[n*NAFF + o] = (float)(tot / 784.0);
  }
}

// ---------- Kernel 4: ego SAM map (f64 stats) ----------
__global__ __launch_bounds__(256) void k_sam(
    const float* __restrict__ attn, float* __restrict__ sam)
{
  __shared__ double sredd[8];
  int tid = threadIdx.x, b = blockIdx.x;
  const int heads[3] = {0, 1, 3};
  float macc[4] = {0,0,0,0};
  for (int hh = 0; hh < 3; hh++) {
    const float* ap = attn + ((size_t)b*6 + heads[hh])*HWD;
    float av[4]; double s = 0.0;
    #pragma unroll
    for (int j = 0; j < 4; j++){ int p = tid + j*256; av[j] = (p < HWD) ? ap[p] : 0.f; s += (double)av[j]; }
    double tot = bsumd<4>(s, sredd, tid);
    double mean = tot / 784.0;
    #pragma unroll
    for (int j = 0; j < 4; j++){ int p = tid + j*256; if (p < HWD) macc[j] += ((double)av[j] > mean) ? 1.f : 0.f; }
  }
  double mn = 1e300, mx = -1e300;
  double mv[4];
  #pragma unroll
  for (int j = 0; j < 4; j++){
    int p = tid + j*256;
    mv[j] = (double)macc[j] / 3.0;
    if (p < HWD){ mn = fmin(mn, mv[j]); mx = fmax(mx, mv[j]); }
  }
  mn = bmind<4>(mn, sredd, tid);
  mx = bmaxd<4>(mx, sredd, tid);
  #pragma unroll
  for (int j = 0; j < 4; j++){
    int p = tid + j*256;
    if (p < HWD) sam[(size_t)b*HWD + p] = (float)((mv[j]-mn)/(mx-mn+1e-12));
  }
}

// ---------- Kernel 5: per-sample KMeans (lane-per-point, f64 decisions) + similarity + IoU ----------
__global__ __launch_bounds__(1024) void k_persample(
    const float* __restrict__ exo, const float* __restrict__ ego,
    const double* __restrict__ aff_cam, const int* __restrict__ labels,
    const float* __restrict__ sam_ws, float* __restrict__ xTc,
    float* __restrict__ out_sim, float* __restrict__ out_exosim,
    float* __restrict__ out_ps, float* __restrict__ out_proto)
{
  __shared__ __align__(16) double s_cent[KCL][CCH];    // 9.2KB
  __shared__ __align__(16) float  s_centf[KCL][CCH];   // 4.6KB
  __shared__ float s_wts[PPTS];                        // 9.4KB
  __shared__ int   s_cidx[PPTS];                       // 9.4KB compacted weighted indices
  __shared__ unsigned char s_assign[PPTS];             // 2.3KB
  __shared__ float s_wsum[16][KCL][CCH];               // 73.7KB
  __shared__ float s_wcnt[16][KCL];
  __shared__ double s_csq[KCL];
  __shared__ double s_redd[20];
  __shared__ float s_red[20];
  __shared__ float s_sim[KCL][HWD];                    // 9.4KB
  __shared__ float s_sam[HWD];                         // 3.1KB
  __shared__ int   s_init[KCL];
  __shared__ float s_cnt[KCL];
  __shared__ float s_ps[KCL];
  __shared__ int   s_valid, s_am, s_pflag, s_npw;

  int tid = threadIdx.x, b = blockIdx.x;
  int wid = tid >> 6, lane = tid & 63;
  int lab = labels[b];

  // P1: cam minmax -> wts, all f64
  for (int e = 0; e < NE; e++) {
    const double* cp = aff_cam + ((size_t)(b*NE + e)*NAFF + lab)*HWD;
    double mn = 1e300, mx = -1e300;
    for (int p = tid; p < HWD; p += 1024){ double v = cp[p]; mn = fmin(mn, v); mx = fmax(mx, v); }
    mn = bmind<16>(mn, s_redd, tid);
    mx = bmaxd<16>(mx, s_redd, tid);
    double den = mx - mn + 1e-10;
    for (int p = tid; p < HWD; p += 1024)
      s_wts[e*HWD + p] = (((cp[p] - mn) / den) > 0.6) ? 1.f : 0.f;
  }
  __syncthreads();
  float nv = 0.f;
  for (int i = tid; i < PPTS; i += 1024) nv += s_wts[i];
  nv = bsum<16>(nv, s_red, tid);
  if (tid == 0) s_valid = (nv >= 3.f) ? 1 : 0;
  __syncthreads();

  // P2a: compact weighted indices (ascending) via wave-0 scan
  if (wid == 0) {
    int cnt = 0;
    for (int base = 0; base < PPTS; base += 64) {
      int i = base + lane;
      bool hit = (i < PPTS) && (s_wts[i] > 0.5f);
      unsigned long long m = __ballot(hit);
      int rank = __popcll(m & ((lane == 0) ? 0ull : ((~0ull) >> (64 - lane))));
      if (hit) s_cidx[cnt + rank] = i;
      cnt += (int)__popcll(m);
    }
    if (lane == 0) s_npw = cnt;
  }

  // P2b: deterministic top-k init (selected ascending, then unselected ascending)
  if (wid == 1 || (gridDim.x == 0)) {} // (placement keeps wave0 free; init done by wave 1)
  if (wid == 1) {
    int found = 0; int idx0 = 0, idx1 = 1, idx2 = 2;
    for (int pass = 0; pass < 2 && found < 3; pass++) {
      for (int base = 0; base < PPTS && found < 3; base += 64) {
        int i = base + lane;
        bool hit;
        if (pass == 0) hit = (i < PPTS) && (s_wts[i] > 0.5f);
        else           hit = (i < PPTS) && (s_wts[i] <= 0.5f);
        unsigned long long mask = __ballot(hit);
        while (mask && found < 3) {
          int bit = (int)(__ffsll((unsigned long long)mask)) - 1;
          int id = base + bit;
          if (found == 0) idx0 = id; else if (found == 1) idx1 = id; else idx2 = id;
          found++;
          mask &= mask - 1;
        }
      }
    }
    if (lane == 0){ s_init[0] = idx0; s_init[1] = idx1; s_init[2] = idx2; }
  }
  __syncthreads();
  for (int i = tid; i < KCL*CCH; i += 1024) {
    int k = i / CCH, c = i % CCH;
    int pi = s_init[k];
    s_cent[k][c] = (double)exo[((size_t)(b*NE)*HWD + pi)*CCH + c];
  }
  int npw = s_npw;
  size_t boff = (size_t)b * ((size_t)CCH * PPTS);   // 903168 per sample

  // P2c: transpose compacted weighted points -> xTc[c][ci] (coalesced Phase-A loads)
  for (int ci = wid; ci < npw; ci += 16) {
    int p = s_cidx[ci];
    const float* bp = exo + ((size_t)(b*NE)*HWD + p)*CCH;
    #pragma unroll
    for (int j = 0; j < 6; j++)
      xTc[boff + (size_t)(lane + 64*j)*PPTS + ci] = bp[lane + 64*j];
  }
  __syncthreads();

  // P3: KMeans
  for (int it = 0; it < KM_ITERS; it++) {
    if (wid < KCL) {
      double q = 0.0;
      #pragma unroll
      for (int j = 0; j < 6; j++){ double v = s_cent[wid][lane + 64*j]; q += v*v; }
      q = wsumd(q);
      if (lane == 0) s_csq[wid] = q;
    }
    for (int i = tid; i < 16*KCL*CCH; i += 1024) ((float*)s_wsum)[i] = 0.f;
    if (tid < 16*KCL) ((float*)s_wcnt)[tid] = 0.f;
    __syncthreads();

    // Phase A: lane-per-point f64 dots + argmin (p_sq cancels in argmin)
    for (int ci = tid; ci < npw; ci += 1024) {
      const float* xp = xTc + boff + ci;
      double dd0 = 0.0, dd1 = 0.0, dd2 = 0.0;
      #pragma unroll 4
      for (int c = 0; c < CCH; c++) {
        double xv = (double)xp[(size_t)c*PPTS];
        dd0 += xv*s_cent[0][c];
        dd1 += xv*s_cent[1][c];
        dd2 += xv*s_cent[2][c];
      }
      double e0 = s_csq[0] - 2.0*dd0;
      double e1 = s_csq[1] - 2.0*dd1;
      double e2 = s_csq[2] - 2.0*dd2;
      int a = 0; double best = e0;
      if (e1 < best){ a = 1; best = e1; }
      if (e2 < best){ a = 2; }
      s_assign[ci] = (unsigned char)a;
    }
    __syncthreads();

    // Phase B: per-wave f32 partial sums (lane = c-dim), no dots
    float l0[6] = {0,0,0,0,0,0}, l1[6] = {0,0,0,0,0,0}, l2[6] = {0,0,0,0,0,0};
    int c0 = 0, c1 = 0, c2 = 0;
    for (int ci = wid; ci < npw; ci += 16) {
      int p = s_cidx[ci];
      const float* bp = exo + ((size_t)(b*NE)*HWD + p)*CCH;
      int a = s_assign[ci];
      float x[6];
      #pragma unroll
      for (int j = 0; j < 6; j++) x[j] = bp[lane + 64*j];
      if (a == 0){ for (int j = 0; j < 6; j++) l0[j] += x[j]; c0++; }
      else if (a == 1){ for (int j = 0; j < 6; j++) l1[j] += x[j]; c1++; }
      else { for (int j = 0; j < 6; j++) l2[j] += x[j]; c2++; }
    }
    #pragma unroll
    for (int j = 0; j < 6; j++){
      s_wsum[wid][0][lane + 64*j] = l0[j];
      s_wsum[wid][1][lane + 64*j] = l1[j];
      s_wsum[wid][2][lane + 64*j] = l2[j];
    }
    if (lane == 0){ s_wcnt[wid][0] = (float)c0; s_wcnt[wid][1] = (float)c1; s_wcnt[wid][2] = (float)c2; }
    __syncthreads();
    if (tid < KCL) {
      float cn = 0.f;
      for (int w = 0; w < 16; w++) cn += s_wcnt[w][tid];
      s_cnt[tid] = cn;
    }
    __syncthreads();
    for (int i = tid; i < KCL*CCH; i += 1024) {
      int k = i / CCH, c = i % CCH;
      double s = 0.0;
      for (int w = 0; w < 16; w++) s += (double)s_wsum[w][k][c];
      float cn = s_cnt[k];
      if (cn > 0.f) s_cent[k][c] = s / (double)cn;
    }
    __syncthreads();
  }

  // P4: l2 normalize centroids (f64), then f32 copy
  if (wid < KCL) {
    double q = 0.0;
    #pragma unroll
    for (int j = 0; j < 6; j++){ double v = s_cent[wid][lane + 64*j]; q += v*v; }
    q = wsumd(q);
    double nrm = fmax(sqrt(q), 1e-12);
    #pragma unroll
    for (int j = 0; j < 6; j++) s_cent[wid][lane + 64*j] = s_cent[wid][lane + 64*j] / nrm;
  }
  __syncthreads();
  for (int i = tid; i < KCL*CCH; i += 1024)
    ((float*)s_centf)[i] = (float)((double*)s_cent)[i];
  __syncthreads();
  int valid = s_valid;

  // P5: exo similarity maps
  for (int i = wid; i < PPTS; i += 16) {
    int e = i / HWD, p = i % HWD;
    const float* bp = exo + ((size_t)(b*NE)*HWD + i)*CCH;
    float x[6];
    #pragma unroll
    for (int j = 0; j < 6; j++) x[j] = bp[lane + 64*j];
    float pn = 0.f, d0 = 0.f, d1 = 0.f, d2 = 0.f;
    #pragma unroll
    for (int j = 0; j < 6; j++){
      int c = lane + 64*j; float xv = x[j];
      pn += xv*xv; d0 += xv*s_centf[0][c]; d1 += xv*s_centf[1][c]; d2 += xv*s_centf[2][c];
    }
    pn = wsum(pn); d0 = wsum(d0); d1 = wsum(d1); d2 = wsum(d2);
    float rn = 1.f/fmaxf(sqrtf(pn), 1e-12f);
    if (lane < 3) {
      float dv = (lane == 0) ? d0 : ((lane == 1) ? d1 : d2);
      out_exosim[(((size_t)(b*NE) + e)*KCL + lane)*HWD + p] = valid ? dv*rn : 0.f;
    }
  }

  // P6: ego similarity
  for (int p = wid; p < HWD; p += 16) {
    const float* bp = ego + ((size_t)b*HWD + p)*CCH;
    float x[6];
    #pragma unroll
    for (int j = 0; j < 6; j++) x[j] = bp[lane + 64*j];
    float pn = 0.f, d0 = 0.f, d1 = 0.f, d2 = 0.f;
    #pragma unroll
    for (int j = 0; j < 6; j++){
      int c = lane + 64*j; float xv = x[j];
      pn += xv*xv; d0 += xv*s_centf[0][c]; d1 += xv*s_centf[1][c]; d2 += xv*s_centf[2][c];
    }
    pn = wsum(pn); d0 = wsum(d0); d1 = wsum(d1); d2 = wsum(d2);
    float rn = 1.f/fmaxf(sqrtf(pn), 1e-12f);
    if (lane < 3){
      float dv = (lane == 0) ? d0 : ((lane == 1) ? d1 : d2);
      s_sim[lane][p] = dv*rn;
    }
  }
  for (int p = tid; p < HWD; p += 1024) s_sam[p] = sam_ws[(size_t)b*HWD + p];
  __syncthreads();

  // P7: IoU-style part score
  float ssv = 0.f;
  for (int p = tid; p < HWD; p += 1024) ssv += s_sam[p];
  float sam_mean = bsum<16>(ssv, s_red, tid) * (1.f/784.f);
  float shv = 0.f;
  for (int p = tid; p < HWD; p += 1024) shv += (s_sam[p] > sam_mean) ? 1.f : 0.f;
  float sam_hard_sum = bsum<16>(shv, s_red, tid);

  for (int k = 0; k < KCL; k++) {
    float mn = 1e30f, mx = -1e30f;
    for (int p = tid; p < HWD; p += 1024){ float v = s_sim[k][p]; mn = fminf(mn, v); mx = fmaxf(mx, v); }
    mn = bmin<16>(mn, s_red, tid);
    mx = bmax<16>(mx, s_red, tid);
    float den = mx - mn + 1e-12f;
    float sns = 0.f;
    for (int p = tid; p < HWD; p += 1024) sns += (s_sim[k][p]-mn)/den;
    float mean_n = bsum<16>(sns, s_red, tid) * (1.f/784.f);
    float hsv = 0.f, isv = 0.f;
    for (int p = tid; p < HWD; p += 1024) {
      float sn = (s_sim[k][p]-mn)/den;
      float hd = (sn > mean_n) ? 1.f : 0.f;
      hsv += hd;
      isv += hd*((s_sam[p] > sam_mean) ? 1.f : 0.f);
    }
    float hsum = bsum<16>(hsv, s_red, tid);
    float isum = bsum<16>(isv, s_red, tid);
    float uni = hsum + sam_hard_sum - isum;
    float pk = 0.5f*(isum/(hsum + 1e-12f) + sam_hard_sum/(uni + 1e-12f));
    if (tid == 0) s_ps[k] = valid ? pk : 0.f;
  }
  __syncthreads();

  // P8: outputs
  for (int i = tid; i < KCL*HWD; i += 1024) {
    int k = i / HWD, p = i % HWD;
    out_sim[((size_t)b*KCL + k)*HWD + p] = valid ? s_sim[k][p] : 0.f;
  }
  if (tid < KCL) out_ps[b*KCL + tid] = s_ps[tid];
  if (tid == 0) {
    int am = 0; float pm = s_ps[0];
    if (s_ps[1] > pm){ am = 1; pm = s_ps[1]; }
    if (s_ps[2] > pm){ am = 2; pm = s_ps[2]; }
    s_am = am;
    s_pflag = (valid && pm >= 0.6f) ? 1 : 0;
  }
  __syncthreads();
  for (int c = tid; c < CCH; c += 1024)
    out_proto[(size_t)b*CCH + c] = s_pflag ? s_centf[s_am][c] : 0.f;
}

extern "C" void kernel_launch(void* const* d_in, const int* in_sizes, int n_in,
                              void* d_out, int out_size, void* d_ws, size_t ws_size,
                              hipStream_t stream) {
  const float* ego  = (const float*)d_in[0];
  const float* exo  = (const float*)d_in[1];
  const float* attn = (const float*)d_in[2];
  const int*   lab  = (const int*)d_in[3];
  const float* ln_g = (const float*)d_in[4];
  const float* ln_b = (const float*)d_in[5];
  const float* w1   = (const float*)d_in[6];
  const float* b1   = (const float*)d_in[7];
  const float* w2   = (const float*)d_in[8];
  const float* b2   = (const float*)d_in[9];
  const float* c1w  = (const float*)d_in[10];
  const float* c1b  = (const float*)d_in[11];
  const float* bn1g = (const float*)d_in[12];
  const float* bn1b = (const float*)d_in[13];
  const float* bn1m = (const float*)d_in[14];
  const float* bn1v = (const float*)d_in[15];
  const float* c2w  = (const float*)d_in[16];
  const float* c2b  = (const float*)d_in[17];
  const float* bn2g = (const float*)d_in[18];
  const float* bn2b = (const float*)d_in[19];
  const float* bn2m = (const float*)d_in[20];
  const float* bn2v = (const float*)d_in[21];
  const float* fw   = (const float*)d_in[22];
  const float* fb   = (const float*)d_in[23];

  float* out = (float*)d_out;
  float* o_logits = out;                               // [16,3,6]
  float* o_sim    = out + 288;                         // [16,3,784]
  float* o_exosim = out + 288 + 37632;                 // [16,3,3,784]
  float* o_ps     = out + 288 + 37632 + 112896;        // [16,3]
  float* o_proto  = out + 288 + 37632 + 112896 + 48;   // [16,384]

  float* ws   = (float*)d_ws;
  float* buf0 = ws;                                      // 48*384*784 f32
  float* buf1 = buf0 + (size_t)48*CCH*HWD;               // 48*384*784 f32 (reused as xTc by k_persample)
  double* affc_d = (double*)(buf1 + (size_t)48*CCH*HWD); // 48*6*784 f64 (8B-aligned offset)
  float* samb = (float*)(affc_d + (size_t)48*NAFF*HWD);  // 16*784 f32

  k_mlp<<<2352, 256, 0, stream>>>(exo, ln_g, ln_b, w1, b1, w2, b2, buf0);
  k_conv<<<2016, 256, 0, stream>>>(buf0, c1w, c1b, bn1g, bn1b, bn1m, bn1v, buf1);
  k_conv<<<2016, 256, 0, stream>>>(buf1, c2w, c2b, bn2g, bn2b, bn2m, bn2v, buf0);
  k_aff<<<48, 1024, 0, stream>>>(buf0, fw, fb, affc_d, o_logits);
  k_sam<<<16, 256, 0, stream>>>(attn, samb);
  // buf1 is dead after conv2 -> reuse as the compacted/transposed point buffer
  k_persample<<<16, 1024, 0, stream>>>(exo, ego, affc_d, lab, samb, buf1,
                                       o_sim, o_exosim, o_ps, o_proto);
}

// Round 8
// 13510.484 us; speedup vs baseline: 1.8463x; 1.0367x over previous
//
#include <hip/hip_runtime.h>
#include <math.h>

#define NBS 16
#define NE 3
#define CCH 384
#define HWD 784
#define C4 1536
#define KCL 3
#define NAFF 6
#define PPTS (NE*HWD)      // 2352
#define KM_ITERS 50

// ---------- wave / block reduction helpers ----------
__device__ __forceinline__ float wsum(float v){
  #pragma unroll
  for (int m = 32; m; m >>= 1) v += __shfl_xor(v, m, 64);
  return v;
}
__device__ __forceinline__ float wmin(float v){
  #pragma unroll
  for (int m = 32; m; m >>= 1) v = fminf(v, __shfl_xor(v, m, 64));
  return v;
}
__device__ __forceinline__ float wmax(float v){
  #pragma unroll
  for (int m = 32; m; m >>= 1) v = fmaxf(v, __shfl_xor(v, m, 64));
  return v;
}
__device__ __forceinline__ double shfl_xor_d(double v, int m){
  long long l = __double_as_longlong(v);
  int lo = (int)(l & 0xffffffffLL), hi = (int)(l >> 32);
  lo = __shfl_xor(lo, m, 64); hi = __shfl_xor(hi, m, 64);
  return __longlong_as_double(((long long)hi << 32) | (unsigned long long)(unsigned int)lo);
}
__device__ __forceinline__ double wsumd(double v){
  #pragma unroll
  for (int m = 32; m; m >>= 1) v += shfl_xor_d(v, m);
  return v;
}
__device__ __forceinline__ double wmind(double v){
  #pragma unroll
  for (int m = 32; m; m >>= 1) v = fmin(v, shfl_xor_d(v, m));
  return v;
}
__device__ __forceinline__ double wmaxd(double v){
  #pragma unroll
  for (int m = 32; m; m >>= 1) v = fmax(v, shfl_xor_d(v, m));
  return v;
}
template<int NW>
__device__ float bsum(float v, float* sred, int tid){
  v = wsum(v);
  __syncthreads();
  if ((tid & 63) == 0) sred[tid >> 6] = v;
  __syncthreads();
  if (tid == 0){ float a = 0.f; for (int w = 0; w < NW; w++) a += sred[w]; sred[NW] = a; }
  __syncthreads();
  return sred[NW];
}
template<int NW>
__device__ float bmin(float v, float* sred, int tid){
  v = wmin(v);
  __syncthreads();
  if ((tid & 63) == 0) sred[tid >> 6] = v;
  __syncthreads();
  if (tid == 0){ float a = sred[0]; for (int w = 1; w < NW; w++) a = fminf(a, sred[w]); sred[NW] = a; }
  __syncthreads();
  return sred[NW];
}
template<int NW>
__device__ float bmax(float v, float* sred, int tid){
  v = wmax(v);
  __syncthreads();
  if ((tid & 63) == 0) sred[tid >> 6] = v;
  __syncthreads();
  if (tid == 0){ float a = sred[0]; for (int w = 1; w < NW; w++) a = fmaxf(a, sred[w]); sred[NW] = a; }
  __syncthreads();
  return sred[NW];
}
template<int NW>
__device__ double bsumd(double v, double* sd, int tid){
  v = wsumd(v);
  __syncthreads();
  if ((tid & 63) == 0) sd[tid >> 6] = v;
  __syncthreads();
  if (tid == 0){ double a = 0.0; for (int w = 0; w < NW; w++) a += sd[w]; sd[NW] = a; }
  __syncthreads();
  return sd[NW];
}
template<int NW>
__device__ double bmind(double v, double* sd, int tid){
  v = wmind(v);
  __syncthreads();
  if ((tid & 63) == 0) sd[tid >> 6] = v;
  __syncthreads();
  if (tid == 0){ double a = sd[0]; for (int w = 1; w < NW; w++) a = fmin(a, sd[w]); sd[NW] = a; }
  __syncthreads();
  return sd[NW];
}
template<int NW>
__device__ double bmaxd(double v, double* sd, int tid){
  v = wmaxd(v);
  __syncthreads();
  if ((tid & 63) == 0) sd[tid >> 6] = v;
  __syncthreads();
  if (tid == 0){ double a = sd[0]; for (int w = 1; w < NW; w++) a = fmax(a, sd[w]); sd[NW] = a; }
  __syncthreads();
  return sd[NW];
}

// ---------- Kernel 0: convert MLP weights to f64 (staged in dead buf1 space) ----------
__global__ __launch_bounds__(256) void k_w64(
    const float* __restrict__ w1, const float* __restrict__ w2,
    double* __restrict__ w1d, double* __restrict__ w2d)
{
  int i = blockIdx.x*256 + threadIdx.x;
  const int N = CCH*C4;
  if (i < N) { w1d[i] = (double)w1[i]; w2d[i] = (double)w2[i]; }
}

// ---------- Kernel 1: LayerNorm -> fc1 -> GELU -> fc2 (+residual), f64 acc ----------
// Stride-20 LDS tiles (bank-conflict-free b128), pre-converted f64 weights (no cvt in hot loop).
__global__ __launch_bounds__(256) void k_mlp(
    const float* __restrict__ exo, const float* __restrict__ ln_g, const float* __restrict__ ln_b,
    const double* __restrict__ w1d, const float* __restrict__ b1,
    const double* __restrict__ w2d, const float* __restrict__ b2,
    float* __restrict__ out)
{
  __shared__ __align__(16) float xs_t[CCH][20];   // [k][token(16)+pad4], 30.7KB
  __shared__ __align__(16) float hs_t[256][20];   // [k][token+pad], 20.5KB
  int tid = threadIdx.x;
  int t0 = blockIdx.x * 16;
  int wv = tid >> 6, lane = tid & 63;

  // LayerNorm in f64 (two-pass), wave handles 4 tokens; writes transposed f32
  for (int tt = 0; tt < 4; tt++) {
    int tok = wv*4 + tt;
    size_t base = (size_t)(t0 + tok)*CCH;
    float xv[6];
    double s = 0.0;
    #pragma unroll
    for (int j = 0; j < 6; j++){ xv[j] = exo[base + lane + 64*j]; s += (double)xv[j]; }
    s = wsumd(s);
    double mu = s / 384.0;
    double q = 0.0;
    #pragma unroll
    for (int j = 0; j < 6; j++){ double d = (double)xv[j] - mu; q += d*d; }
    q = wsumd(q);
    double sdev = sqrt(q / 384.0 + 1e-5);
    #pragma unroll
    for (int j = 0; j < 6; j++){
      int c = lane + 64*j;
      xs_t[c][tok] = (float)(((double)xv[j] - mu)/sdev*(double)ln_g[c] + (double)ln_b[c]);
    }
  }
  __syncthreads();

  int u = tid & 63;   // GEMM1: cols u*4..u*4+3 of jb chunk; GEMM2: out cols u*6..u*6+5
  int tg = tid >> 6;  // tokens tg*4 .. tg*4+3

  double acc[4][6];
  #pragma unroll
  for (int t = 0; t < 4; t++)
    #pragma unroll
    for (int c = 0; c < 6; c++) acc[t][c] = 0.0;

  for (int jb = 0; jb < 6; jb++) {
    // ---- GEMM1: h[tok][jb*256+u*4+c] = sum_r xn[tok][r]*w1[r][col]
    double hacc[4][4];
    #pragma unroll
    for (int t = 0; t < 4; t++)
      #pragma unroll
      for (int c = 0; c < 4; c++) hacc[t][c] = 0.0;
    const double* w1p = w1d + jb*256 + u*4;
    #pragma unroll 2
    for (int r = 0; r < 384; r++) {
      float4 xq = *(const float4*)&xs_t[r][tg*4];
      const double* wr = w1p + (size_t)r*C4;
      double2 wa = *(const double2*)&wr[0];
      double2 wb = *(const double2*)&wr[2];
      double xd[4] = {(double)xq.x,(double)xq.y,(double)xq.z,(double)xq.w};
      double wd[4] = {wa.x, wa.y, wb.x, wb.y};
      #pragma unroll
      for (int t = 0; t < 4; t++)
        #pragma unroll
        for (int c = 0; c < 4; c++) hacc[t][c] += xd[t]*wd[c];
    }
    __syncthreads();   // prior GEMM2 finished reading hs_t
    // bias + exact GELU (f64), float4-over-token stores (conflict-free)
    #pragma unroll
    for (int c = 0; c < 4; c++) {
      int col = jb*256 + u*4 + c;
      double bb = (double)b1[col];
      float hv[4];
      #pragma unroll
      for (int t = 0; t < 4; t++) {
        double h = hacc[t][c] + bb;
        h = 0.5*h*(1.0 + erf(h*0.70710678118654752440));
        hv[t] = (float)h;
      }
      *(float4*)&hs_t[u*4+c][tg*4] = make_float4(hv[0],hv[1],hv[2],hv[3]);
    }
    __syncthreads();
    // ---- GEMM2 partial: acc[tok][outc] += sum_k h[tok][k]*w2[jb*256+k][outc]
    const double* w2p = w2d + (size_t)(jb*256)*CCH + u*6;
    #pragma unroll 2
    for (int k = 0; k < 256; k++) {
      float4 hq = *(const float4*)&hs_t[k][tg*4];
      double hd[4] = {(double)hq.x,(double)hq.y,(double)hq.z,(double)hq.w};
      const double* wr = w2p + (size_t)k*CCH;
      double2 wa = *(const double2*)&wr[0];
      double2 wb = *(const double2*)&wr[2];
      double2 wc = *(const double2*)&wr[4];
      double wd[6] = {wa.x, wa.y, wb.x, wb.y, wc.x, wc.y};
      #pragma unroll
      for (int t = 0; t < 4; t++)
        #pragma unroll
        for (int c = 0; c < 6; c++) acc[t][c] += hd[t]*wd[c];
    }
  }

  // epilogue: residual + b2, write NCHW
  #pragma unroll
  for (int t = 0; t < 4; t++) {
    int T = t0 + tg*4 + t;
    int n = T / HWD, p = T % HWD;
    #pragma unroll
    for (int c6 = 0; c6 < 6; c6++) {
      int c = u*6 + c6;
      double y = (double)exo[(size_t)T*CCH + c] + (acc[t][c6] + (double)b2[c]);
      out[((size_t)n*CCH + c)*HWD + p] = (float)y;
    }
  }
}

// ---------- Kernel 2: conv3x3 SAME + bias + BN + ReLU, f64 acc, 32 co/block (occupancy) ----------
__global__ __launch_bounds__(256) void k_conv(
    const float* __restrict__ in, const float* __restrict__ w, const float* __restrict__ bias,
    const float* __restrict__ bng, const float* __restrict__ bnb,
    const float* __restrict__ bnm, const float* __restrict__ bnv,
    float* __restrict__ out)
{
  __shared__ float xt[8*198];        // 8 ci x 6 rows x 33 cols (halo-padded), 6.3KB
  __shared__ float wt[32][8][12];    // 12.3KB
  int tid = threadIdx.x;
  int blk = blockIdx.x;
  int n = blk / 84; int rem = blk % 84;
  int cob = rem / 7, pxb = rem % 7;
  int co0 = cob*32, r0 = pxb*4;
  int pxg = tid & 15, cog = tid >> 4;          // cog in [0,16): co = co0 + cog*2 + q
  int rr = pxg >> 2, c0 = (pxg & 3)*7;

  double acc[2][7];
  #pragma unroll
  for (int q = 0; q < 2; q++)
    #pragma unroll
    for (int i = 0; i < 7; i++) acc[q][i] = 0.0;

  for (int cb = 0; cb < 48; cb++) {
    __syncthreads();
    for (int i = tid; i < 8*198; i += 256) {
      int ci = i / 198; int r2 = i % 198; int r6 = r2 / 33; int col = r2 % 33;
      int r = r0 + r6 - 1, wc = col - 1;
      xt[i] = (r >= 0 && r < 28 && wc >= 0 && wc < 28)
                ? in[((size_t)n*CCH + cb*8 + ci)*HWD + r*28 + wc] : 0.f;
    }
    for (int i = tid; i < 32*8*12; i += 256) {
      int co = i / 96; int r2 = i % 96; int ci = r2 / 12; int t = r2 % 12;
      wt[co][ci][t] = (t < 9) ? w[((size_t)(co0 + co)*CCH + cb*8 + ci)*9 + t] : 0.f;
    }
    __syncthreads();
    #pragma unroll
    for (int ci = 0; ci < 8; ci++) {
      #pragma unroll
      for (int dy = 0; dy < 3; dy++) {
        const float* xr = &xt[ci*198 + (rr+dy)*33 + c0];
        double xd[9];
        #pragma unroll
        for (int j = 0; j < 9; j++) xd[j] = (double)xr[j];
        #pragma unroll
        for (int q = 0; q < 2; q++) {
          const float* wp = &wt[cog*2 + q][ci][dy*3];
          double w0 = (double)wp[0], w1d = (double)wp[1], w2d = (double)wp[2];
          #pragma unroll
          for (int i7 = 0; i7 < 7; i7++) {
            acc[q][i7] += xd[i7]*w0;
            acc[q][i7] += xd[i7+1]*w1d;
            acc[q][i7] += xd[i7+2]*w2d;
          }
        }
      }
    }
  }
  #pragma unroll
  for (int q = 0; q < 2; q++) {
    int co = co0 + cog*2 + q;
    double sdev = sqrt((double)bnv[co] + 1e-5);
    double gg = (double)bng[co], bb = (double)bnb[co], mm = (double)bnm[co], bc = (double)bias[co];
    #pragma unroll
    for (int i7 = 0; i7 < 7; i7++) {
      double y = acc[q][i7] + bc;
      y = (y - mm)/sdev*gg + bb;
      y = fmax(y, 0.0);
      out[((size_t)n*CCH + co)*HWD + (r0+rr)*28 + c0 + i7] = (float)y;
    }
  }
}

// ---------- Kernel 3: 1x1 conv head (f64) + logits; writes f64 aff_cam ----------
__global__ __launch_bounds__(1024) void k_aff(
    const float* __restrict__ x, const float* __restrict__ fw, const float* __restrict__ fb,
    double* __restrict__ aff_cam, float* __restrict__ logits)
{
  __shared__ double swd[NAFF*CCH];   // 18.4KB, pre-converted weights
  __shared__ double sredd[17];
  int tid = threadIdx.x, n = blockIdx.x;
  for (int i = tid; i < NAFF*CCH; i += 1024) swd[i] = (double)fw[i];
  __syncthreads();
  int px = tid;
  double acc[NAFF] = {0,0,0,0,0,0};
  if (px < HWD) {
    for (int c = 0; c < CCH; c++) {
      double xv = (double)x[((size_t)n*CCH + c)*HWD + px];
      #pragma unroll
      for (int o = 0; o < NAFF; o++) acc[o] += xv * swd[o*CCH + c];
    }
  }
  for (int o = 0; o < NAFF; o++) {
    double val = 0.0;
    if (px < HWD) {
      val = acc[o] + (double)fb[o];
      aff_cam[((size_t)n*NAFF + o)*HWD + px] = val;
    }
    double tot = bsumd<16>(val, sredd, tid);
    if (tid == 0) logits[n*NAFF + o] = (float)(tot / 784.0);
  }
}

// ---------- Kernel 4: ego SAM map (f64 stats) ----------
__global__ __launch_bounds__(256) void k_sam(
    const float* __restrict__ attn, float* __restrict__ sam)
{
  __shared__ double sredd[8];
  int tid = threadIdx.x, b = blockIdx.x;
  const int heads[3] = {0, 1, 3};
  float macc[4] = {0,0,0,0};
  for (int hh = 0; hh < 3; hh++) {
    const float* ap = attn + ((size_t)b*6 + heads[hh])*HWD;
    float av[4]; double s = 0.0;
    #pragma unroll
    for (int j = 0; j < 4; j++){ int p = tid + j*256; av[j] = (p < HWD) ? ap[p] : 0.f; s += (double)av[j]; }
    double tot = bsumd<4>(s, sredd, tid);
    double mean = tot / 784.0;
    #pragma unroll
    for (int j = 0; j < 4; j++){ int p = tid + j*256; if (p < HWD) macc[j] += ((double)av[j] > mean) ? 1.f : 0.f; }
  }
  double mn = 1e300, mx = -1e300;
  double mv[4];
  #pragma unroll
  for (int j = 0; j < 4; j++){
    int p = tid + j*256;
    mv[j] = (double)macc[j] / 3.0;
    if (p < HWD){ mn = fmin(mn, mv[j]); mx = fmax(mx, mv[j]); }
  }
  mn = bmind<4>(mn, sredd, tid);
  mx = bmaxd<4>(mx, sredd, tid);
  #pragma unroll
  for (int j = 0; j < 4; j++){
    int p = tid + j*256;
    if (p < HWD) sam[(size_t)b*HWD + p] = (float)((mv[j]-mn)/(mx-mn+1e-12));
  }
}

// ---------- Kernel 5: per-sample KMeans (lane-per-point, f64 decisions) + similarity + IoU ----------
__global__ __launch_bounds__(1024) void k_persample(
    const float* __restrict__ exo, const float* __restrict__ ego,
    const double* __restrict__ aff_cam, const int* __restrict__ labels,
    const float* __restrict__ sam_ws, float* __restrict__ xTc,
    float* __restrict__ out_sim, float* __restrict__ out_exosim,
    float* __restrict__ out_ps, float* __restrict__ out_proto)
{
  __shared__ __align__(16) double s_cent[KCL][CCH];
  __shared__ __align__(16) float  s_centf[KCL][CCH];
  __shared__ float s_wts[PPTS];
  __shared__ int   s_cidx[PPTS];
  __shared__ unsigned char s_assign[PPTS];
  __shared__ float s_wsum[16][KCL][CCH];
  __shared__ float s_wcnt[16][KCL];
  __shared__ double s_csq[KCL];
  __shared__ double s_redd[20];
  __shared__ float s_red[20];
  __shared__ float s_sim[KCL][HWD];
  __shared__ float s_sam[HWD];
  __shared__ int   s_init[KCL];
  __shared__ float s_cnt[KCL];
  __shared__ float s_ps[KCL];
  __shared__ int   s_valid, s_am, s_pflag, s_npw;

  int tid = threadIdx.x, b = blockIdx.x;
  int wid = tid >> 6, lane = tid & 63;
  int lab = labels[b];

  // P1: cam minmax -> wts, all f64
  for (int e = 0; e < NE; e++) {
    const double* cp = aff_cam + ((size_t)(b*NE + e)*NAFF + lab)*HWD;
    double mn = 1e300, mx = -1e300;
    for (int p = tid; p < HWD; p += 1024){ double v = cp[p]; mn = fmin(mn, v); mx = fmax(mx, v); }
    mn = bmind<16>(mn, s_redd, tid);
    mx = bmaxd<16>(mx, s_redd, tid);
    double den = mx - mn + 1e-10;
    for (int p = tid; p < HWD; p += 1024)
      s_wts[e*HWD + p] = (((cp[p] - mn) / den) > 0.6) ? 1.f : 0.f;
  }
  __syncthreads();
  float nv = 0.f;
  for (int i = tid; i < PPTS; i += 1024) nv += s_wts[i];
  nv = bsum<16>(nv, s_red, tid);
  if (tid == 0) s_valid = (nv >= 3.f) ? 1 : 0;
  __syncthreads();

  // P2a: compact weighted indices (ascending) via wave-0 scan
  if (wid == 0) {
    int cnt = 0;
    for (int base = 0; base < PPTS; base += 64) {
      int i = base + lane;
      bool hit = (i < PPTS) && (s_wts[i] > 0.5f);
      unsigned long long m = __ballot(hit);
      int rank = __popcll(m & ((lane == 0) ? 0ull : ((~0ull) >> (64 - lane))));
      if (hit) s_cidx[cnt + rank] = i;
      cnt += (int)__popcll(m);
    }
    if (lane == 0) s_npw = cnt;
  }

  // P2b: deterministic top-k init (selected ascending, then unselected ascending)
  if (wid == 1) {
    int found = 0; int idx0 = 0, idx1 = 1, idx2 = 2;
    for (int pass = 0; pass < 2 && found < 3; pass++) {
      for (int base = 0; base < PPTS && found < 3; base += 64) {
        int i = base + lane;
        bool hit;
        if (pass == 0) hit = (i < PPTS) && (s_wts[i] > 0.5f);
        else           hit = (i < PPTS) && (s_wts[i] <= 0.5f);
        unsigned long long mask = __ballot(hit);
        while (mask && found < 3) {
          int bit = (int)(__ffsll((unsigned long long)mask)) - 1;
          int id = base + bit;
          if (found == 0) idx0 = id; else if (found == 1) idx1 = id; else idx2 = id;
          found++;
          mask &= mask - 1;
        }
      }
    }
    if (lane == 0){ s_init[0] = idx0; s_init[1] = idx1; s_init[2] = idx2; }
  }
  __syncthreads();
  for (int i = tid; i < KCL*CCH; i += 1024) {
    int k = i / CCH, c = i % CCH;
    int pi = s_init[k];
    s_cent[k][c] = (double)exo[((size_t)(b*NE)*HWD + pi)*CCH + c];
  }
  int npw = s_npw;
  size_t boff = (size_t)b * ((size_t)CCH * PPTS);

  // P2c: transpose compacted weighted points -> xTc[c][ci]
  for (int ci = wid; ci < npw; ci += 16) {
    int p = s_cidx[ci];
    const float* bp = exo + ((size_t)(b*NE)*HWD + p)*CCH;
    #pragma unroll
    for (int j = 0; j < 6; j++)
      xTc[boff + (size_t)(lane + 64*j)*PPTS + ci] = bp[lane + 64*j];
  }
  __syncthreads();

  // P3: KMeans
  for (int it = 0; it < KM_ITERS; it++) {
    if (wid < KCL) {
      double q = 0.0;
      #pragma unroll
      for (int j = 0; j < 6; j++){ double v = s_cent[wid][lane + 64*j]; q += v*v; }
      q = wsumd(q);
      if (lane == 0) s_csq[wid] = q;
    }
    for (int i = tid; i < 16*KCL*CCH; i += 1024) ((float*)s_wsum)[i] = 0.f;
    if (tid < 16*KCL) ((float*)s_wcnt)[tid] = 0.f;
    __syncthreads();

    // Phase A: lane-per-point f64 dots + argmin (p_sq cancels in argmin)
    for (int ci = tid; ci < npw; ci += 1024) {
      const float* xp = xTc + boff + ci;
      double dd0 = 0.0, dd1 = 0.0, dd2 = 0.0;
      #pragma unroll 4
      for (int c = 0; c < CCH; c++) {
        double xv = (double)xp[(size_t)c*PPTS];
        dd0 += xv*s_cent[0][c];
        dd1 += xv*s_cent[1][c];
        dd2 += xv*s_cent[2][c];
      }
      double e0 = s_csq[0] - 2.0*dd0;
      double e1 = s_csq[1] - 2.0*dd1;
      double e2 = s_csq[2] - 2.0*dd2;
      int a = 0; double best = e0;
      if (e1 < best){ a = 1; best = e1; }
      if (e2 < best){ a = 2; }
      s_assign[ci] = (unsigned char)a;
    }
    __syncthreads();

    // Phase B: per-wave f32 partial sums (lane = c-dim)
    float l0[6] = {0,0,0,0,0,0}, l1[6] = {0,0,0,0,0,0}, l2[6] = {0,0,0,0,0,0};
    int c0 = 0, c1 = 0, c2 = 0;
    for (int ci = wid; ci < npw; ci += 16) {
      int p = s_cidx[ci];
      const float* bp = exo + ((size_t)(b*NE)*HWD + p)*CCH;
      int a = s_assign[ci];
      float x[6];
      #pragma unroll
      for (int j = 0; j < 6; j++) x[j] = bp[lane + 64*j];
      if (a == 0){ for (int j = 0; j < 6; j++) l0[j] += x[j]; c0++; }
      else if (a == 1){ for (int j = 0; j < 6; j++) l1[j] += x[j]; c1++; }
      else { for (int j = 0; j < 6; j++) l2[j] += x[j]; c2++; }
    }
    #pragma unroll
    for (int j = 0; j < 6; j++){
      s_wsum[wid][0][lane + 64*j] = l0[j];
      s_wsum[wid][1][lane + 64*j] = l1[j];
      s_wsum[wid][2][lane + 64*j] = l2[j];
    }
    if (lane == 0){ s_wcnt[wid][0] = (float)c0; s_wcnt[wid][1] = (float)c1; s_wcnt[wid][2] = (float)c2; }
    __syncthreads();
    if (tid < KCL) {
      float cn = 0.f;
      for (int w = 0; w < 16; w++) cn += s_wcnt[w][tid];
      s_cnt[tid] = cn;
    }
    __syncthreads();
    for (int i = tid; i < KCL*CCH; i += 1024) {
      int k = i / CCH, c = i % CCH;
      double s = 0.0;
      for (int w = 0; w < 16; w++) s += (double)s_wsum[w][k][c];
      float cn = s_cnt[k];
      if (cn > 0.f) s_cent[k][c] = s / (double)cn;
    }
    __syncthreads();
  }

  // P4: l2 normalize centroids (f64), then f32 copy
  if (wid < KCL) {
    double q = 0.0;
    #pragma unroll
    for (int j = 0; j < 6; j++){ double v = s_cent[wid][lane + 64*j]; q += v*v; }
    q = wsumd(q);
    double nrm = fmax(sqrt(q), 1e-12);
    #pragma unroll
    for (int j = 0; j < 6; j++) s_cent[wid][lane + 64*j] = s_cent[wid][lane + 64*j] / nrm;
  }
  __syncthreads();
  for (int i = tid; i < KCL*CCH; i += 1024)
    ((float*)s_centf)[i] = (float)((double*)s_cent)[i];
  __syncthreads();
  int valid = s_valid;

  // P5: exo similarity maps
  for (int i = wid; i < PPTS; i += 16) {
    int e = i / HWD, p = i % HWD;
    const float* bp = exo + ((size_t)(b*NE)*HWD + i)*CCH;
    float x[6];
    #pragma unroll
    for (int j = 0; j < 6; j++) x[j] = bp[lane + 64*j];
    float pn = 0.f, d0 = 0.f, d1 = 0.f, d2 = 0.f;
    #pragma unroll
    for (int j = 0; j < 6; j++){
      int c = lane + 64*j; float xv = x[j];
      pn += xv*xv; d0 += xv*s_centf[0][c]; d1 += xv*s_centf[1][c]; d2 += xv*s_centf[2][c];
    }
    pn = wsum(pn); d0 = wsum(d0); d1 = wsum(d1); d2 = wsum(d2);
    float rn = 1.f/fmaxf(sqrtf(pn), 1e-12f);
    if (lane < 3) {
      float dv = (lane == 0) ? d0 : ((lane == 1) ? d1 : d2);
      out_exosim[(((size_t)(b*NE) + e)*KCL + lane)*HWD + p] = valid ? dv*rn : 0.f;
    }
  }

  // P6: ego similarity
  for (int p = wid; p < HWD; p += 16) {
    const float* bp = ego + ((size_t)b*HWD + p)*CCH;
    float x[6];
    #pragma unroll
    for (int j = 0; j < 6; j++) x[j] = bp[lane + 64*j];
    float pn = 0.f, d0 = 0.f, d1 = 0.f, d2 = 0.f;
    #pragma unroll
    for (int j = 0; j < 6; j++){
      int c = lane + 64*j; float xv = x[j];
      pn += xv*xv; d0 += xv*s_centf[0][c]; d1 += xv*s_centf[1][c]; d2 += xv*s_centf[2][c];
    }
    pn = wsum(pn); d0 = wsum(d0); d1 = wsum(d1); d2 = wsum(d2);
    float rn = 1.f/fmaxf(sqrtf(pn), 1e-12f);
    if (lane < 3){
      float dv = (lane == 0) ? d0 : ((lane == 1) ? d1 : d2);
      s_sim[lane][p] = dv*rn;
    }
  }
  for (int p = tid; p < HWD; p += 1024) s_sam[p] = sam_ws[(size_t)b*HWD + p];
  __syncthreads();

  // P7: IoU-style part score
  float ssv = 0.f;
  for (int p = tid; p < HWD; p += 1024) ssv += s_sam[p];
  float sam_mean = bsum<16>(ssv, s_red, tid) * (1.f/784.f);
  float shv = 0.f;
  for (int p = tid; p < HWD; p += 1024) shv += (s_sam[p] > sam_mean) ? 1.f : 0.f;
  float sam_hard_sum = bsum<16>(shv, s_red, tid);

  for (int k = 0; k < KCL; k++) {
    float mn = 1e30f, mx = -1e30f;
    for (int p = tid; p < HWD; p += 1024){ float v = s_sim[k][p]; mn = fminf(mn, v); mx = fmaxf(mx, v); }
    mn = bmin<16>(mn, s_red, tid);
    mx = bmax<16>(mx, s_red, tid);
    float den = mx - mn + 1e-12f;
    float sns = 0.f;
    for (int p = tid; p < HWD; p += 1024) sns += (s_sim[k][p]-mn)/den;
    float mean_n = bsum<16>(sns, s_red, tid) * (1.f/784.f);
    float hsv = 0.f, isv = 0.f;
    for (int p = tid; p < HWD; p += 1024) {
      float sn = (s_sim[k][p]-mn)/den;
      float hd = (sn > mean_n) ? 1.f : 0.f;
      hsv += hd;
      isv += hd*((s_sam[p] > sam_mean) ? 1.f : 0.f);
    }
    float hsum = bsum<16>(hsv, s_red, tid);
    float isum = bsum<16>(isv, s_red, tid);
    float uni = hsum + sam_hard_sum - isum;
    float pk = 0.5f*(isum/(hsum + 1e-12f) + sam_hard_sum/(uni + 1e-12f));
    if (tid == 0) s_ps[k] = valid ? pk : 0.f;
  }
  __syncthreads();

  // P8: outputs
  for (int i = tid; i < KCL*HWD; i += 1024) {
    int k = i / HWD, p = i % HWD;
    out_sim[((size_t)b*KCL + k)*HWD + p] = valid ? s_sim[k][p] : 0.f;
  }
  if (tid < KCL) out_ps[b*KCL + tid] = s_ps[tid];
  if (tid == 0) {
    int am = 0; float pm = s_ps[0];
    if (s_ps[1] > pm){ am = 1; pm = s_ps[1]; }
    if (s_ps[2] > pm){ am = 2; pm = s_ps[2]; }
    s_am = am;
    s_pflag = (valid && pm >= 0.6f) ? 1 : 0;
  }
  __syncthreads();
  for (int c = tid; c < CCH; c += 1024)
    out_proto[(size_t)b*CCH + c] = s_pflag ? s_centf[s_am][c] : 0.f;
}

extern "C" void kernel_launch(void* const* d_in, const int* in_sizes, int n_in,
                              void* d_out, int out_size, void* d_ws, size_t ws_size,
                              hipStream_t stream) {
  const float* ego  = (const float*)d_in[0];
  const float* exo  = (const float*)d_in[1];
  const float* attn = (const float*)d_in[2];
  const int*   lab  = (const int*)d_in[3];
  const float* ln_g = (const float*)d_in[4];
  const float* ln_b = (const float*)d_in[5];
  const float* w1   = (const float*)d_in[6];
  const float* b1   = (const float*)d_in[7];
  const float* w2   = (const float*)d_in[8];
  const float* b2   = (const float*)d_in[9];
  const float* c1w  = (const float*)d_in[10];
  const float* c1b  = (const float*)d_in[11];
  const float* bn1g = (const float*)d_in[12];
  const float* bn1b = (const float*)d_in[13];
  const float* bn1m = (const float*)d_in[14];
  const float* bn1v = (const float*)d_in[15];
  const float* c2w  = (const float*)d_in[16];
  const float* c2b  = (const float*)d_in[17];
  const float* bn2g = (const float*)d_in[18];
  const float* bn2b = (const float*)d_in[19];
  const float* bn2m = (const float*)d_in[20];
  const float* bn2v = (const float*)d_in[21];
  const float* fw   = (const float*)d_in[22];
  const float* fb   = (const float*)d_in[23];

  float* out = (float*)d_out;
  float* o_logits = out;                               // [16,3,6]
  float* o_sim    = out + 288;                         // [16,3,784]
  float* o_exosim = out + 288 + 37632;                 // [16,3,3,784]
  float* o_ps     = out + 288 + 37632 + 112896;        // [16,3]
  float* o_proto  = out + 288 + 37632 + 112896 + 48;   // [16,384]

  float* ws   = (float*)d_ws;
  float* buf0 = ws;                                      // 48*384*784 f32
  float* buf1 = buf0 + (size_t)48*CCH*HWD;               // 48*384*784 f32
  double* affc_d = (double*)(buf1 + (size_t)48*CCH*HWD); // 48*6*784 f64
  float* samb = (float*)(affc_d + (size_t)48*NAFF*HWD);  // 16*784 f32

  // f64 weights staged in buf1 (dead until conv1 writes it; byte offset is 8-aligned)
  double* w1d = (double*)buf1;                // 384*1536 f64 = 4.72MB
  double* w2d = w1d + (size_t)CCH*C4;         // 4.72MB

  k_w64<<<(CCH*C4 + 255)/256, 256, 0, stream>>>(w1, w2, w1d, w2d);
  k_mlp<<<2352, 256, 0, stream>>>(exo, ln_g, ln_b, w1d, b1, w2d, b2, buf0);
  k_conv<<<4032, 256, 0, stream>>>(buf0, c1w, c1b, bn1g, bn1b, bn1m, bn1v, buf1);
  k_conv<<<4032, 256, 0, stream>>>(buf1, c2w, c2b, bn2g, bn2b, bn2m, bn2v, buf0);
  k_aff<<<48, 1024, 0, stream>>>(buf0, fw, fb, affc_d, o_logits);
  k_sam<<<16, 256, 0, stream>>>(attn, samb);
  k_persample<<<16, 1024, 0, stream>>>(exo, ego, affc_d, lab, samb, buf1,
                                       o_sim, o_exosim, o_ps, o_proto);
}